// Round 2
// baseline (62829.553 us; speedup 1.0000x reference)
//
#include <hip/hip_runtime.h>
#include <math.h>

#define BATCH 32
#define LEN   160000
#define NFFT  512
#define NT    626
#define NF    257
#define HID   512
#define PROJN 5140
#define TC    32          // tail chunk (timesteps)
#define NCHUNK 20         // ceil(626/32)

__device__ __forceinline__ float sigm(float x){ return 1.0f/(1.0f+expf(-x)); }

// ---------------- init: twiddle table + zero state region ----------------
__global__ __launch_bounds__(256) void k_init(float* tw, float* zr, int nz){
  int i = blockIdx.x*256 + threadIdx.x;
  if (i < 512){
    float ang = 6.28318530717958647692f * (float)i / 512.0f;
    tw[i]     = cosf(ang);
    tw[512+i] = sinf(ang);
  }
  for (int j = i; j < nz; j += gridDim.x*256) zr[j] = 0.f;
}

__global__ __launch_bounds__(256) void k_zero(float* p, int n){
  for (int i = blockIdx.x*256 + threadIdx.x; i < n; i += gridDim.x*256) p[i] = 0.f;
}

// ---------------- fused STFT + mag^0.5 + LayerNorm: one block per (b,t) ----------------
__global__ __launch_bounds__(256) void k_stftln(const float* __restrict__ x, const float* __restrict__ tw,
                                                const float* __restrict__ g, const float* __restrict__ be,
                                                float* __restrict__ hln){
  int b = blockIdx.x / NT;
  int t = blockIdx.x % NT;
  __shared__ float fr[NFFT], lc[NFFT], ls[NFFT], mg[NF];
  __shared__ float red[16];
  const float* xb = x + (size_t)b*LEN;
  for (int n = threadIdx.x; n < NFFT; n += 256){
    lc[n] = tw[n]; ls[n] = tw[512+n];
    int j = t*256 + n - 256;              // reflect pad
    if (j < 0) j = -j;
    else if (j >= LEN) j = 2*LEN - 2 - j;
    fr[n] = xb[j] * (0.5f - 0.5f*tw[n]);  // hann window
  }
  __syncthreads();
  float v=0.f, v2=0.f;
  for (int f = threadIdx.x; f < NF; f += 256){
    float ar = 0.f, ai = 0.f;
    int idx = 0;
    #pragma unroll 8
    for (int n = 0; n < NFFT; n++){
      float vv = fr[n];
      ar += vv*lc[idx];
      ai -= vv*ls[idx];
      idx = (idx + f) & 511;
    }
    float m = sqrtf(sqrtf(ar*ar + ai*ai));   // |spec|^0.5
    mg[f]=m; v+=m; v2+=m*m;
  }
  for (int off=32; off; off>>=1){ v += __shfl_down(v,off); v2 += __shfl_down(v2,off); }
  int w = threadIdx.x >> 6;
  if ((threadIdx.x & 63)==0){ red[w]=v; red[8+w]=v2; }
  __syncthreads();
  if (threadIdx.x==0){
    float s  = red[0]+red[1]+red[2]+red[3];
    float s2 = red[8]+red[9]+red[10]+red[11];
    float mu = s/(float)NF;
    red[4]=mu;
    red[5]=rsqrtf(s2/(float)NF - mu*mu + 1e-5f);
  }
  __syncthreads();
  float mu=red[4], rs=red[5];
  size_t ob = ((size_t)t*BATCH + b)*NF;
  for (int f=threadIdx.x; f<NF; f+=256)
    hln[ob+f] = (mg[f]-mu)*rs*g[f] + be[f];
}

// ---------------- STFT for a tail chunk: frames t = tb0+tt, layout [b][f][36] ----------------
__global__ __launch_bounds__(256) void k_stft_chunk(const float* __restrict__ x, const float* __restrict__ tw,
                                                    float* __restrict__ spR, float* __restrict__ spI, int tb0){
  int tt = blockIdx.x;         // 0..35
  int b  = blockIdx.y;
  int t  = tb0 + tt;
  if (t < 0 || t >= NT){
    for (int f = threadIdx.x; f < NF; f += 256){
      size_t o = ((size_t)b*NF + f)*36 + tt;
      spR[o]=0.f; spI[o]=0.f;
    }
    return;
  }
  __shared__ float fr[NFFT], lc[NFFT], ls[NFFT];
  const float* xb = x + (size_t)b*LEN;
  for (int n = threadIdx.x; n < NFFT; n += 256){
    lc[n] = tw[n]; ls[n] = tw[512+n];
    int j = t*256 + n - 256;
    if (j < 0) j = -j;
    else if (j >= LEN) j = 2*LEN - 2 - j;
    fr[n] = xb[j] * (0.5f - 0.5f*tw[n]);
  }
  __syncthreads();
  for (int f = threadIdx.x; f < NF; f += 256){
    float ar = 0.f, ai = 0.f;
    int idx = 0;
    #pragma unroll 8
    for (int n = 0; n < NFFT; n++){
      float vv = fr[n];
      ar += vv*lc[idx];
      ai -= vv*ls[idx];
      idx = (idx + f) & 511;
    }
    size_t o = ((size_t)b*NF + f)*36 + tt;
    spR[o] = ar; spI[o] = ai;
  }
}

// ---------------- fp32 GEMM: C[M,N] = A[M,K]*Bm[N,K]^T + bias, tanh ----------------
__global__ __launch_bounds__(256) void k_gemm_tanh(const float* __restrict__ A, const float* __restrict__ Bm,
                                                   const float* __restrict__ bias,
                                                   float* __restrict__ C, int M, int N, int K){
  __shared__ float As[16][65];
  __shared__ float Bs[16][65];
  int bm = blockIdx.y*64, bn = blockIdx.x*64;
  int tx = threadIdx.x & 15, ty = threadIdx.x >> 4;
  float acc[4][4] = {};
  for (int k0=0; k0<K; k0+=16){
    for (int i=threadIdx.x; i<1024; i+=256){
      int r=i>>4, c=i&15;
      int kk=k0+c;
      As[c][r] = A[(size_t)(bm+r)*K + kk];              // M mult of 64, K mult of 16
      int nn=bn+r;
      Bs[c][r] = (nn<N) ? Bm[(size_t)nn*K + kk] : 0.f;
    }
    __syncthreads();
    #pragma unroll
    for (int kk=0; kk<16; kk++){
      float a[4], bb[4];
      #pragma unroll
      for (int i=0;i<4;i++) a[i]=As[kk][ty*4+i];
      #pragma unroll
      for (int j=0;j<4;j++) bb[j]=Bs[kk][tx*4+j];
      #pragma unroll
      for (int i=0;i<4;i++)
        #pragma unroll
        for (int j=0;j<4;j++)
          acc[i][j] += a[i]*bb[j];
    }
    __syncthreads();
  }
  for (int i=0;i<4;i++){
    int m = bm + ty*4 + i;
    for (int j=0;j<4;j++){
      int n = bn + tx*4 + j;
      if (n < N)
        C[(size_t)m*N + n] = tanhf(acc[i][j] + bias[n]);
    }
  }
}

// ---------------- LSTM step: blocks 0..63 = layer0 step t, blocks 64..127 = layer1 step t-1 ----------------
__global__ __launch_bounds__(256) void k_step(int t,
    const float* __restrict__ hln,
    const float* __restrict__ Wih0, const float* __restrict__ Whh0,
    const float* __restrict__ bih0, const float* __restrict__ bhh0,
    const float* __restrict__ Wih1, const float* __restrict__ Whh1,
    const float* __restrict__ bih1, const float* __restrict__ bhh1,
    float* __restrict__ hs0r, float* __restrict__ hs1r,
    float* __restrict__ c0, float* __restrict__ c1){
  int layer = blockIdx.x >> 6;
  if (layer==0 && t>=NT) return;
  if (layer==1 && t==0) return;
  int ub = (blockIdx.x & 63)*8;
  __shared__ float xs[32][65];
  __shared__ float Wt[32][65];
  int b  = threadIdx.x & 31;
  int uh = threadIdx.x >> 5;
  float acc[4] = {0.f,0.f,0.f,0.f};
  for (int pass=0; pass<2; pass++){
    const float* inv; const float* Wm; int K;
    if (layer==0){
      if (pass==0){ inv = hln + (size_t)t*BATCH*NF; K=NF; Wm=Wih0; }
      else { if (t==0) continue;
             inv = hs0r + (size_t)((t-1)&3)*BATCH*HID; K=HID; Wm=Whh0; }
    } else {
      if (pass==0){ inv = hs0r + (size_t)((t-1)&3)*BATCH*HID; K=HID; Wm=Wih1; }
      else { int tau=t-1; if (tau==0) continue;
             inv = hs1r + (size_t)((tau-1)&63)*BATCH*HID; K=HID; Wm=Whh1; }
    }
    for (int k0=0; k0<K; k0+=64){
      for (int i=threadIdx.x; i<2048; i+=256){
        int r=i>>6, kk=i&63;
        int k=k0+kk;
        int gate=r>>3, ul=r&7;
        xs[r][kk] = (k<K) ? inv[(size_t)r*K + k] : 0.f;
        Wt[r][kk] = (k<K) ? Wm[(size_t)(gate*HID + ub + ul)*K + k] : 0.f;
      }
      __syncthreads();
      #pragma unroll 16
      for (int kk=0; kk<64; kk++){
        float xv = xs[b][kk];
        acc[0] += xv * Wt[uh][kk];
        acc[1] += xv * Wt[8+uh][kk];
        acc[2] += xv * Wt[16+uh][kk];
        acc[3] += xv * Wt[24+uh][kk];
      }
      __syncthreads();
    }
  }
  int u = ub + uh;
  if (layer==0){
    acc[0] += bih0[0*HID+u] + bhh0[0*HID+u];
    acc[1] += bih0[1*HID+u] + bhh0[1*HID+u];
    acc[2] += bih0[2*HID+u] + bhh0[2*HID+u];
    acc[3] += bih0[3*HID+u] + bhh0[3*HID+u];
  } else {
    acc[0] += bih1[0*HID+u] + bhh1[0*HID+u];
    acc[1] += bih1[1*HID+u] + bhh1[1*HID+u];
    acc[2] += bih1[2*HID+u] + bhh1[2*HID+u];
    acc[3] += bih1[3*HID+u] + bhh1[3*HID+u];
  }
  float* cst = layer ? c1 : c0;
  float cold = cst[b*HID + u];
  float ig = sigm(acc[0]);
  float fg = sigm(acc[1]);
  float gg = tanhf(acc[2]);
  float og = sigm(acc[3]);
  float cn = fg*cold + ig*gg;
  float hn = og*tanhf(cn);
  cst[b*HID + u] = cn;
  if (layer==0)
    hs0r[(size_t)(t&3)*BATCH*HID + b*HID + u] = hn;
  else {
    int tau = t-1;
    hs1r[(size_t)(tau&63)*BATCH*HID + b*HID + u] = hn;
  }
}

// ---------------- fused deep-filter + irfft + window + OLA(atomic): block per (tl,b,s) ----------------
__global__ __launch_bounds__(256) void k_ifused(const float* __restrict__ prch,
    const float* __restrict__ spR, const float* __restrict__ spI,
    const float* __restrict__ tw, float* __restrict__ out, int tb0){
  int tl = blockIdx.x >> 6;           // local timestep in chunk
  int b  = (blockIdx.x >> 1) & 31;
  int s  = blockIdx.x & 1;
  int tau = tb0 + 4 + tl;             // absolute frame
  __shared__ float re[NF], im[NF], lc[NFFT], ls[NFFT];
  for (int i=threadIdx.x; i<NFFT; i+=256){ lc[i]=tw[i]; ls[i]=tw[512+i]; }
  const float* p = prch + ((size_t)tl*BATCH + b)*PROJN;
  for (int f=threadIdx.x; f<NF; f+=256){
    float ar=0.f, ai=0.f;
    size_t so = ((size_t)b*NF + f)*36;
    #pragma unroll
    for (int d=0; d<5; d++){
      int ts = tb0 + tl + d;
      if (ts >= 0){
        float sr=spR[so + tl + d], si=spI[so + tl + d];
        float cr=p[d*514 + s*257 + f];
        float ci=p[2570 + d*514 + s*257 + f];
        ar += sr*cr - si*ci;
        ai += sr*ci + si*cr;
      }
    }
    re[f]=ar; im[f]=ai;
  }
  __syncthreads();
  float* ob = out + (size_t)(b*2+s)*LEN;
  for (int n=threadIdx.x; n<NFFT; n+=256){
    float acc = re[0] + ((n&1) ? -re[256] : re[256]);
    int idx = n;
    #pragma unroll 8
    for (int k=1; k<256; k++){
      acc += 2.f*(re[k]*lc[idx] - im[k]*ls[idx]);
      idx = (idx + n) & 511;
    }
    int pos = tau*256 - 256 + n;      // unpadded output position
    if (pos >= 0 && pos < LEN)
      atomicAdd(ob + pos, acc * (1.0f/512.0f) * (0.5f - 0.5f*lc[n]));
  }
}

// ---------------- normalize by wsq (exactly 2 frames per sample) ----------------
__global__ __launch_bounds__(256) void k_norm(float* __restrict__ out, const float* __restrict__ tw, int n){
  for (int i = blockIdx.x*256 + threadIdx.x; i < n; i += gridDim.x*256){
    int m = (i % LEN) & 255;
    float cm = tw[m];
    float w1 = 0.5f - 0.5f*cm;
    float w2 = 0.5f + 0.5f*cm;
    out[i] = out[i] / (w1*w1 + w2*w2);
  }
}

extern "C" void kernel_launch(void* const* d_in, const int* in_sizes, int n_in,
                              void* d_out, int out_size, void* d_ws, size_t ws_size,
                              hipStream_t stream){
  const float* x     = (const float*)d_in[0];
  const float* ln_g  = (const float*)d_in[1];
  const float* ln_b  = (const float*)d_in[2];
  const float* Wih0  = (const float*)d_in[3];
  const float* Whh0  = (const float*)d_in[4];
  const float* bih0  = (const float*)d_in[5];
  const float* bhh0  = (const float*)d_in[6];
  const float* Wih1  = (const float*)d_in[7];
  const float* Whh1  = (const float*)d_in[8];
  const float* bih1  = (const float*)d_in[9];
  const float* bhh1  = (const float*)d_in[10];
  const float* projW = (const float*)d_in[11];
  const float* projb = (const float*)d_in[12];

  float* W = (float*)d_ws;
  // layout (floats), total ~12.15M floats = ~48.6 MiB
  float* tw   = W;                                       // 1024
  float* hln  = tw + 1024;                               // NT*B*NF     = 5,148,224
  float* spR  = hln + (size_t)NT*BATCH*NF;               // B*NF*36     =   296,064
  float* spI  = spR + (size_t)BATCH*NF*36;               //               296,064
  float* prch = spI + (size_t)BATCH*NF*36;               // TC*B*PROJN  = 5,263,360
  float* hs0r = prch + (size_t)TC*BATCH*PROJN;           // 4*B*HID     =    65,536
  float* hs1r = hs0r + (size_t)4*BATCH*HID;              // 64*B*HID    = 1,048,576
  float* c0   = hs1r + (size_t)64*BATCH*HID;             // B*HID       =    16,384
  float* c1   = c0 + BATCH*HID;                          //                 16,384
  int nz = (4+64)*BATCH*HID + 2*BATCH*HID;               // hs0r..c1 contiguous

  k_init<<<1024, 256, 0, stream>>>(tw, hs0r, nz);
  k_zero<<<2048, 256, 0, stream>>>((float*)d_out, out_size);
  k_stftln<<<BATCH*NT, 256, 0, stream>>>(x, tw, ln_g, ln_b, hln);

  for (int t=0; t<=NT; t++){
    k_step<<<128, 256, 0, stream>>>(t, hln, Wih0, Whh0, bih0, bhh0,
                                    Wih1, Whh1, bih1, bhh1, hs0r, hs1r, c0, c1);
    if (t >= TC && (t % TC)==0){
      int c = t/TC - 1;
      int tb0 = c*TC - 4;
      int tcc = TC;   // chunks 0..18 are full
      k_stft_chunk<<<dim3(36, BATCH), 256, 0, stream>>>(x, tw, spR, spI, tb0);
      dim3 gp((PROJN+63)/64, (tcc*BATCH)/64);
      k_gemm_tanh<<<gp, 256, 0, stream>>>(hs1r + (size_t)((c*TC)&63)*BATCH*HID, projW, projb,
                                          prch, tcc*BATCH, PROJN, HID);
      k_ifused<<<tcc*64, 256, 0, stream>>>(prch, spR, spI, tw, (float*)d_out, tb0);
    }
  }
  {  // last chunk c=19: taus 608..625 (18 steps)
    int c = NCHUNK-1;
    int tb0 = c*TC - 4;
    int tcc = NT - c*TC;   // 18
    k_stft_chunk<<<dim3(36, BATCH), 256, 0, stream>>>(x, tw, spR, spI, tb0);
    dim3 gp((PROJN+63)/64, (tcc*BATCH)/64);
    k_gemm_tanh<<<gp, 256, 0, stream>>>(hs1r + (size_t)((c*TC)&63)*BATCH*HID, projW, projb,
                                        prch, tcc*BATCH, PROJN, HID);
    k_ifused<<<tcc*64, 256, 0, stream>>>(prch, spR, spI, tw, (float*)d_out, tb0);
  }

  k_norm<<<2048, 256, 0, stream>>>((float*)d_out, tw, out_size);
}

// Round 3
// 31798.816 us; speedup vs baseline: 1.9758x; 1.9758x over previous
//
#include <hip/hip_runtime.h>
#include <hip/hip_cooperative_groups.h>
#include <math.h>

namespace cg = cooperative_groups;

#define BATCH 32
#define LEN   160000
#define NFFT  512
#define NT    626
#define NF    257
#define NFP   288          // NF padded to 9*32
#define HID   512
#define PROJN 5140
#define TC    32
#define NCHUNK 20
#define K0    800          // NFP + HID
#define K1    1024         // HID + HID

typedef unsigned short ushort;
typedef __attribute__((ext_vector_type(8))) short short8;
typedef __attribute__((ext_vector_type(4))) float f32x4;

__device__ __forceinline__ float sigm(float x){ return 1.0f/(1.0f+expf(-x)); }
__device__ __forceinline__ ushort f2bf(float f){
  union{float f;unsigned u;} v; v.f=f;
  unsigned r = v.u + 0x7fffu + ((v.u>>16)&1u);
  return (ushort)(r>>16);
}
__device__ __forceinline__ float bf2f(ushort h){
  union{unsigned u;float f;} v; v.u = ((unsigned)h)<<16;
  return v.f;
}

// ---------------- init: twiddles + zero int region ----------------
__global__ __launch_bounds__(256) void k_init(float* tw, int* zr, int nz){
  int i = blockIdx.x*256 + threadIdx.x;
  if (i < 512){
    float ang = 6.28318530717958647692f * (float)i / 512.0f;
    tw[i]     = cosf(ang);
    tw[512+i] = sinf(ang);
  }
  for (int j = i; j < nz; j += gridDim.x*256) zr[j] = 0;
}

__global__ __launch_bounds__(256) void k_zero(float* p, int n){
  for (int i = blockIdx.x*256 + threadIdx.x; i < n; i += gridDim.x*256) p[i] = 0.f;
}

// ---------------- prep: bf16 weight concat + combined biases ----------------
__global__ __launch_bounds__(256) void k_prep(const float* __restrict__ Wih0, const float* __restrict__ Whh0,
                                              const float* __restrict__ bih0, const float* __restrict__ bhh0,
                                              const float* __restrict__ Wih1, const float* __restrict__ Whh1,
                                              const float* __restrict__ bih1, const float* __restrict__ bhh1,
                                              ushort* __restrict__ W0, ushort* __restrict__ W1,
                                              float* __restrict__ b0c, float* __restrict__ b1c){
  const int n0 = 2048*K0, n1 = 2048*K1;
  for (int i = blockIdx.x*256 + threadIdx.x; i < n0 + n1 + 4096; i += gridDim.x*256){
    if (i < n0){
      int r = i / K0, c = i - r*K0;
      float v = (c < 257) ? Wih0[(size_t)r*257 + c] : (c < NFP ? 0.f : Whh0[(size_t)r*512 + (c-NFP)]);
      W0[i] = f2bf(v);
    } else if (i < n0 + n1){
      int j = i - n0;
      int r = j / K1, c = j - r*K1;
      float v = (c < 512) ? Wih1[(size_t)r*512 + c] : Whh1[(size_t)r*512 + (c-512)];
      W1[j] = f2bf(v);
    } else {
      int j = i - n0 - n1;
      if (j < 2048) b0c[j] = bih0[j] + bhh0[j];
      else          b1c[j-2048] = bih1[j-2048] + bhh1[j-2048];
    }
  }
}

// ---------------- fused STFT + mag^0.5 + LayerNorm -> bf16 padded [t][b][NFP] ----------------
__global__ __launch_bounds__(256) void k_stftln(const float* __restrict__ x, const float* __restrict__ tw,
                                                const float* __restrict__ g, const float* __restrict__ be,
                                                ushort* __restrict__ hlnb){
  int b = blockIdx.x / NT;
  int t = blockIdx.x % NT;
  __shared__ float fr[NFFT], lc[NFFT], ls[NFFT], mg[NF];
  __shared__ float red[16];
  const float* xb = x + (size_t)b*LEN;
  for (int n = threadIdx.x; n < NFFT; n += 256){
    lc[n] = tw[n]; ls[n] = tw[512+n];
    int j = t*256 + n - 256;
    if (j < 0) j = -j;
    else if (j >= LEN) j = 2*LEN - 2 - j;
    fr[n] = xb[j] * (0.5f - 0.5f*tw[n]);
  }
  __syncthreads();
  float v=0.f, v2=0.f;
  for (int f = threadIdx.x; f < NF; f += 256){
    float ar = 0.f, ai = 0.f;
    int idx = 0;
    #pragma unroll 8
    for (int n = 0; n < NFFT; n++){
      float vv = fr[n];
      ar += vv*lc[idx];
      ai -= vv*ls[idx];
      idx = (idx + f) & 511;
    }
    float m = sqrtf(sqrtf(ar*ar + ai*ai));
    mg[f]=m; v+=m; v2+=m*m;
  }
  for (int off=32; off; off>>=1){ v += __shfl_down(v,off); v2 += __shfl_down(v2,off); }
  int w = threadIdx.x >> 6;
  if ((threadIdx.x & 63)==0){ red[w]=v; red[8+w]=v2; }
  __syncthreads();
  if (threadIdx.x==0){
    float s  = red[0]+red[1]+red[2]+red[3];
    float s2 = red[8]+red[9]+red[10]+red[11];
    float mu = s/(float)NF;
    red[4]=mu;
    red[5]=rsqrtf(s2/(float)NF - mu*mu + 1e-5f);
  }
  __syncthreads();
  float mu=red[4], rs=red[5];
  size_t ob = ((size_t)t*BATCH + b)*NFP;
  for (int f=threadIdx.x; f<NFP; f+=256){
    float val = 0.f;
    if (f < NF) val = (mg[f]-mu)*rs*g[f] + be[f];
    hlnb[ob+f] = f2bf(val);
  }
}

// ---------------- cooperative LSTM: both layers, pipelined, MFMA bf16 ----------------
// blocks 0..127: layer0 (units blk*4..+3), blocks 128..255: layer1.
__global__ __launch_bounds__(256, 1) void k_lstm(const ushort* __restrict__ hlnb,
    const ushort* __restrict__ W0, const ushort* __restrict__ W1,
    const float* __restrict__ b0c, const float* __restrict__ b1c,
    ushort* __restrict__ h0b, ushort* __restrict__ h1b,
    float* __restrict__ c0, float* __restrict__ c1,
    ushort* __restrict__ h1hist){
  cg::grid_group grid = cg::this_grid();
  const int blk   = blockIdx.x;
  const int layer = blk >> 7;
  const int u0    = (blk & 127) * 4;
  const int tid   = threadIdx.x;
  const int wave  = tid >> 6;
  const int lane  = tid & 63;
  const int col   = lane & 15;
  const int kg    = lane >> 4;          // 0..3
  const int m0    = (wave & 1) << 4;    // batch tile base
  const int kh    = wave >> 1;          // K half
  __shared__ float pc[2][32][17];

  const ushort* Wm = layer ? W1 : W0;
  const float*  bc = layer ? b1c : b0c;
  float*        cst = layer ? c1 : c0;
  const int K  = layer ? K1 : K0;
  const int KT = K >> 5;                 // 32 or 25
  const int mid = (KT + 1) >> 1;
  const int ktA = kh ? mid : 0;
  const int ktB = kh ? KT : mid;
  // gate-row for this lane's column: col = gate*4 + ul
  const int wrow = ((col >> 2) << 9) + u0 + (col & 3);
  const ushort* wrp = Wm + (size_t)wrow * K;

  for (int t = 0; t <= NT; ++t){
    const bool active = layer ? (t >= 1) : (t < NT);
    if (active){
      const int tau = layer ? (t-1) : t;
      const ushort* h0p = h0b + (size_t)((t-1)&1)*(BATCH*HID);
      f32x4 acc = {0.f,0.f,0.f,0.f};
      for (int kt = ktA; kt < ktB; ++kt){
        int kk = kt << 5;
        const ushort* xbase; int kloc, krow;
        if (layer == 0){
          if (kk < NFP){ xbase = hlnb + (size_t)t*BATCH*NFP; kloc = kk; krow = NFP; }
          else         { xbase = h0p; kloc = kk - NFP; krow = HID; }
        } else {
          if (kk < HID){ xbase = h0p; kloc = kk; krow = HID; }
          else         { xbase = h1b + (size_t)((tau-1)&1)*(BATCH*HID); kloc = kk - HID; krow = HID; }
        }
        short8 a = *(const short8*)(const void*)(xbase + (size_t)(m0 + col)*krow + kloc + kg*8);
        short8 b = *(const short8*)(const void*)(wrp + kk + kg*8);
        acc = __builtin_amdgcn_mfma_f32_16x16x32_bf16(a, b, acc, 0, 0, 0);
      }
      #pragma unroll
      for (int j=0;j<4;j++)
        pc[kh][m0 + (kg<<2) + j][col] = acc[j];
      __syncthreads();
      if (tid < 128){
        int b  = tid & 31;
        int ul = tid >> 5;       // 0..3
        int u  = u0 + ul;
        float pre[4];
        #pragma unroll
        for (int g=0; g<4; g++){
          int cc = (g<<2) + ul;
          pre[g] = pc[0][b][cc] + pc[1][b][cc] + bc[(g<<9) + u];
        }
        float cold = cst[b*HID + u];
        float ig = sigm(pre[0]);
        float fg = sigm(pre[1]);
        float gg = tanhf(pre[2]);
        float og = sigm(pre[3]);
        float cn = fg*cold + ig*gg;
        float hn = og*tanhf(cn);
        cst[b*HID + u] = cn;
        ushort hb = f2bf(hn);
        if (layer == 0){
          h0b[(size_t)(t&1)*(BATCH*HID) + b*HID + u] = hb;
        } else {
          h1b[(size_t)(tau&1)*(BATCH*HID) + b*HID + u] = hb;
          h1hist[(size_t)(tau+1)*(BATCH*HID) + b*HID + u] = hb;
        }
      }
    }
    grid.sync();
  }
}

// ---------------- STFT for a tail chunk: frames t = tb0+tt, layout [b][f][36] ----------------
__global__ __launch_bounds__(256) void k_stft_chunk(const float* __restrict__ x, const float* __restrict__ tw,
                                                    float* __restrict__ spR, float* __restrict__ spI, int tb0){
  int tt = blockIdx.x;
  int b  = blockIdx.y;
  int t  = tb0 + tt;
  if (t < 0 || t >= NT){
    for (int f = threadIdx.x; f < NF; f += 256){
      size_t o = ((size_t)b*NF + f)*36 + tt;
      spR[o]=0.f; spI[o]=0.f;
    }
    return;
  }
  __shared__ float fr[NFFT], lc[NFFT], ls[NFFT];
  const float* xb = x + (size_t)b*LEN;
  for (int n = threadIdx.x; n < NFFT; n += 256){
    lc[n] = tw[n]; ls[n] = tw[512+n];
    int j = t*256 + n - 256;
    if (j < 0) j = -j;
    else if (j >= LEN) j = 2*LEN - 2 - j;
    fr[n] = xb[j] * (0.5f - 0.5f*tw[n]);
  }
  __syncthreads();
  for (int f = threadIdx.x; f < NF; f += 256){
    float ar = 0.f, ai = 0.f;
    int idx = 0;
    #pragma unroll 8
    for (int n = 0; n < NFFT; n++){
      float vv = fr[n];
      ar += vv*lc[idx];
      ai -= vv*ls[idx];
      idx = (idx + f) & 511;
    }
    size_t o = ((size_t)b*NF + f)*36 + tt;
    spR[o] = ar; spI[o] = ai;
  }
}

// ---------------- GEMM: C[M,N] = A_bf16[M,K]*Bm[N,K]^T + bias, tanh ----------------
__global__ __launch_bounds__(256) void k_gemm_tanh(const ushort* __restrict__ A, const float* __restrict__ Bm,
                                                   const float* __restrict__ bias,
                                                   float* __restrict__ C, int M, int N, int K){
  __shared__ float As[16][65];
  __shared__ float Bs[16][65];
  int bm = blockIdx.y*64, bn = blockIdx.x*64;
  int tx = threadIdx.x & 15, ty = threadIdx.x >> 4;
  float acc[4][4] = {};
  for (int k0=0; k0<K; k0+=16){
    for (int i=threadIdx.x; i<1024; i+=256){
      int r=i>>4, c=i&15;
      int kk=k0+c;
      As[c][r] = bf2f(A[(size_t)(bm+r)*K + kk]);
      int nn=bn+r;
      Bs[c][r] = (nn<N) ? Bm[(size_t)nn*K + kk] : 0.f;
    }
    __syncthreads();
    #pragma unroll
    for (int kk=0; kk<16; kk++){
      float a[4], bb[4];
      #pragma unroll
      for (int i=0;i<4;i++) a[i]=As[kk][ty*4+i];
      #pragma unroll
      for (int j=0;j<4;j++) bb[j]=Bs[kk][tx*4+j];
      #pragma unroll
      for (int i=0;i<4;i++)
        #pragma unroll
        for (int j=0;j<4;j++)
          acc[i][j] += a[i]*bb[j];
    }
    __syncthreads();
  }
  for (int i=0;i<4;i++){
    int m = bm + ty*4 + i;
    for (int j=0;j<4;j++){
      int n = bn + tx*4 + j;
      if (n < N)
        C[(size_t)m*N + n] = tanhf(acc[i][j] + bias[n]);
    }
  }
}

// ---------------- fused deep-filter + irfft + window + OLA(atomic) ----------------
__global__ __launch_bounds__(256) void k_ifused(const float* __restrict__ prch,
    const float* __restrict__ spR, const float* __restrict__ spI,
    const float* __restrict__ tw, float* __restrict__ out, int tb0){
  int tl = blockIdx.x >> 6;
  int b  = (blockIdx.x >> 1) & 31;
  int s  = blockIdx.x & 1;
  int tau = tb0 + 4 + tl;
  __shared__ float re[NF], im[NF], lc[NFFT], ls[NFFT];
  for (int i=threadIdx.x; i<NFFT; i+=256){ lc[i]=tw[i]; ls[i]=tw[512+i]; }
  const float* p = prch + ((size_t)tl*BATCH + b)*PROJN;
  for (int f=threadIdx.x; f<NF; f+=256){
    float ar=0.f, ai=0.f;
    size_t so = ((size_t)b*NF + f)*36;
    #pragma unroll
    for (int d=0; d<5; d++){
      int ts = tb0 + tl + d;
      if (ts >= 0){
        float sr=spR[so + tl + d], si=spI[so + tl + d];
        float cr=p[d*514 + s*257 + f];
        float ci=p[2570 + d*514 + s*257 + f];
        ar += sr*cr - si*ci;
        ai += sr*ci + si*cr;
      }
    }
    re[f]=ar; im[f]=ai;
  }
  __syncthreads();
  float* ob = out + (size_t)(b*2+s)*LEN;
  for (int n=threadIdx.x; n<NFFT; n+=256){
    float acc = re[0] + ((n&1) ? -re[256] : re[256]);
    int idx = n;
    #pragma unroll 8
    for (int k=1; k<256; k++){
      acc += 2.f*(re[k]*lc[idx] - im[k]*ls[idx]);
      idx = (idx + n) & 511;
    }
    int pos = tau*256 - 256 + n;
    if (pos >= 0 && pos < LEN)
      atomicAdd(ob + pos, acc * (1.0f/512.0f) * (0.5f - 0.5f*lc[n]));
  }
}

// ---------------- normalize by wsq ----------------
__global__ __launch_bounds__(256) void k_norm(float* __restrict__ out, const float* __restrict__ tw, int n){
  for (int i = blockIdx.x*256 + threadIdx.x; i < n; i += gridDim.x*256){
    int m = (i % LEN) & 255;
    float cm = tw[m];
    float w1 = 0.5f - 0.5f*cm;
    float w2 = 0.5f + 0.5f*cm;
    out[i] = out[i] / (w1*w1 + w2*w2);
  }
}

extern "C" void kernel_launch(void* const* d_in, const int* in_sizes, int n_in,
                              void* d_out, int out_size, void* d_ws, size_t ws_size,
                              hipStream_t stream){
  const float* x     = (const float*)d_in[0];
  const float* ln_g  = (const float*)d_in[1];
  const float* ln_b  = (const float*)d_in[2];
  const float* Wih0  = (const float*)d_in[3];
  const float* Whh0  = (const float*)d_in[4];
  const float* bih0  = (const float*)d_in[5];
  const float* bhh0  = (const float*)d_in[6];
  const float* Wih1  = (const float*)d_in[7];
  const float* Whh1  = (const float*)d_in[8];
  const float* bih1  = (const float*)d_in[9];
  const float* bhh1  = (const float*)d_in[10];
  const float* projW = (const float*)d_in[11];
  const float* projb = (const float*)d_in[12];

  char* base = (char*)d_ws;
  size_t off = 0;
  auto carve = [&](size_t bytes)->char*{
    char* p = base + off;
    off += (bytes + 255) & ~(size_t)255;
    return p;
  };
  float*  tw     = (float*) carve(1024*4);
  ushort* hlnb   = (ushort*)carve((size_t)NT*BATCH*NFP*2);
  ushort* W0     = (ushort*)carve((size_t)2048*K0*2);
  ushort* W1     = (ushort*)carve((size_t)2048*K1*2);
  float*  b0c    = (float*) carve(2048*4);
  float*  b1c    = (float*) carve(2048*4);
  ushort* h0b    = (ushort*)carve((size_t)2*BATCH*HID*2);
  ushort* h1b    = (ushort*)carve((size_t)2*BATCH*HID*2);
  float*  c0     = (float*) carve((size_t)BATCH*HID*4);
  float*  c1     = (float*) carve((size_t)BATCH*HID*4);
  ushort* h1hist = (ushort*)carve((size_t)(NT+1)*BATCH*HID*2);
  float*  spR    = (float*) carve((size_t)BATCH*NF*36*4);
  float*  spI    = (float*) carve((size_t)BATCH*NF*36*4);
  float*  prch   = (float*) carve((size_t)TC*BATCH*PROJN*4);

  // zero region: h0b..c1 contiguous (2*32K + 2*32K bf16 + 2*64K f32 = 256KB+pad)
  int nzInts = (int)(((char*)(c1 + BATCH*HID) - (char*)h0b) / 4);

  k_init<<<512, 256, 0, stream>>>(tw, (int*)h0b, nzInts);
  k_zero<<<2048, 256, 0, stream>>>((float*)d_out, out_size);
  k_prep<<<4096, 256, 0, stream>>>(Wih0, Whh0, bih0, bhh0, Wih1, Whh1, bih1, bhh1,
                                   W0, W1, b0c, b1c);
  k_stftln<<<BATCH*NT, 256, 0, stream>>>(x, tw, ln_g, ln_b, hlnb);

  {
    void* args[] = { (void*)&hlnb, (void*)&W0, (void*)&W1, (void*)&b0c, (void*)&b1c,
                     (void*)&h0b, (void*)&h1b, (void*)&c0, (void*)&c1, (void*)&h1hist };
    hipLaunchCooperativeKernel(reinterpret_cast<void*>(k_lstm), dim3(256), dim3(256),
                               args, 0, stream);
  }

  for (int c = 0; c < NCHUNK; ++c){
    int tb0 = c*TC - 4;
    int tcc = (c == NCHUNK-1) ? (NT - c*TC) : TC;
    k_stft_chunk<<<dim3(36, BATCH), 256, 0, stream>>>(x, tw, spR, spI, tb0);
    dim3 gp((PROJN+63)/64, (tcc*BATCH)/64);
    k_gemm_tanh<<<gp, 256, 0, stream>>>(h1hist + ((size_t)(c*TC)+1)*BATCH*HID, projW, projb,
                                        prch, tcc*BATCH, PROJN, HID);
    k_ifused<<<tcc*64, 256, 0, stream>>>(prch, spR, spI, tw, (float*)d_out, tb0);
  }

  k_norm<<<2048, 256, 0, stream>>>((float*)d_out, tw, out_size);
}

// Round 4
// 16231.319 us; speedup vs baseline: 3.8709x; 1.9591x over previous
//
#include <hip/hip_runtime.h>
#include <hip/hip_cooperative_groups.h>
#include <math.h>

#define BATCH 32
#define LEN   160000
#define NFFT  512
#define NT    626
#define NF    257
#define NFP   288          // NF padded to 9*32
#define HID   512
#define PROJN 5140
#define TC    32
#define NCHUNK 20
#define K0    800          // NFP + HID
#define K1    1024         // HID + HID
#define NBLK  64           // LSTM grid

typedef unsigned short ushort;
typedef __attribute__((ext_vector_type(8))) short short8;
typedef __attribute__((ext_vector_type(4))) float f32x4;

__device__ __forceinline__ float sigm(float x){ return 1.0f/(1.0f+expf(-x)); }
__device__ __forceinline__ ushort f2bf(float f){
  union{float f;unsigned u;} v; v.f=f;
  unsigned r = v.u + 0x7fffu + ((v.u>>16)&1u);
  return (ushort)(r>>16);
}
__device__ __forceinline__ float bf2f(ushort h){
  union{unsigned u;float f;} v; v.u = ((unsigned)h)<<16;
  return v.f;
}

// ---------------- init: twiddles + zero int region ----------------
__global__ __launch_bounds__(256) void k_init(float* tw, int* zr, int nz){
  int i = blockIdx.x*256 + threadIdx.x;
  if (i < 512){
    float ang = 6.28318530717958647692f * (float)i / 512.0f;
    tw[i]     = cosf(ang);
    tw[512+i] = sinf(ang);
  }
  for (int j = i; j < nz; j += gridDim.x*256) zr[j] = 0;
}

__global__ __launch_bounds__(256) void k_zero(float* p, int n){
  for (int i = blockIdx.x*256 + threadIdx.x; i < n; i += gridDim.x*256) p[i] = 0.f;
}

// ---------------- prep: bf16 weight concat + combined biases ----------------
__global__ __launch_bounds__(256) void k_prep(const float* __restrict__ Wih0, const float* __restrict__ Whh0,
                                              const float* __restrict__ bih0, const float* __restrict__ bhh0,
                                              const float* __restrict__ Wih1, const float* __restrict__ Whh1,
                                              const float* __restrict__ bih1, const float* __restrict__ bhh1,
                                              ushort* __restrict__ W0, ushort* __restrict__ W1,
                                              float* __restrict__ b0c, float* __restrict__ b1c){
  const int n0 = 2048*K0, n1 = 2048*K1;
  for (int i = blockIdx.x*256 + threadIdx.x; i < n0 + n1 + 4096; i += gridDim.x*256){
    if (i < n0){
      int r = i / K0, c = i - r*K0;
      float v = (c < 257) ? Wih0[(size_t)r*257 + c] : (c < NFP ? 0.f : Whh0[(size_t)r*512 + (c-NFP)]);
      W0[i] = f2bf(v);
    } else if (i < n0 + n1){
      int j = i - n0;
      int r = j / K1, c = j - r*K1;
      float v = (c < 512) ? Wih1[(size_t)r*512 + c] : Whh1[(size_t)r*512 + (c-512)];
      W1[j] = f2bf(v);
    } else {
      int j = i - n0 - n1;
      if (j < 2048) b0c[j] = bih0[j] + bhh0[j];
      else          b1c[j-2048] = bih1[j-2048] + bhh1[j-2048];
    }
  }
}

// ---------------- fused STFT + mag^0.5 + LayerNorm -> bf16 padded [t][b][NFP] ----------------
__global__ __launch_bounds__(256) void k_stftln(const float* __restrict__ x, const float* __restrict__ tw,
                                                const float* __restrict__ g, const float* __restrict__ be,
                                                ushort* __restrict__ hlnb){
  int b = blockIdx.x / NT;
  int t = blockIdx.x % NT;
  __shared__ float fr[NFFT], lc[NFFT], ls[NFFT], mg[NF];
  __shared__ float red[16];
  const float* xb = x + (size_t)b*LEN;
  for (int n = threadIdx.x; n < NFFT; n += 256){
    lc[n] = tw[n]; ls[n] = tw[512+n];
    int j = t*256 + n - 256;
    if (j < 0) j = -j;
    else if (j >= LEN) j = 2*LEN - 2 - j;
    fr[n] = xb[j] * (0.5f - 0.5f*tw[n]);
  }
  __syncthreads();
  float v=0.f, v2=0.f;
  for (int f = threadIdx.x; f < NF; f += 256){
    float ar = 0.f, ai = 0.f;
    int idx = 0;
    #pragma unroll 8
    for (int n = 0; n < NFFT; n++){
      float vv = fr[n];
      ar += vv*lc[idx];
      ai -= vv*ls[idx];
      idx = (idx + f) & 511;
    }
    float m = sqrtf(sqrtf(ar*ar + ai*ai));
    mg[f]=m; v+=m; v2+=m*m;
  }
  for (int off=32; off; off>>=1){ v += __shfl_down(v,off); v2 += __shfl_down(v2,off); }
  int w = threadIdx.x >> 6;
  if ((threadIdx.x & 63)==0){ red[w]=v; red[8+w]=v2; }
  __syncthreads();
  if (threadIdx.x==0){
    float s  = red[0]+red[1]+red[2]+red[3];
    float s2 = red[8]+red[9]+red[10]+red[11];
    float mu = s/(float)NF;
    red[4]=mu;
    red[5]=rsqrtf(s2/(float)NF - mu*mu + 1e-5f);
  }
  __syncthreads();
  float mu=red[4], rs=red[5];
  size_t ob = ((size_t)t*BATCH + b)*NFP;
  for (int f=threadIdx.x; f<NFP; f+=256){
    float val = 0.f;
    if (f < NF) val = (mg[f]-mu)*rs*g[f] + be[f];
    hlnb[ob+f] = f2bf(val);
  }
}

// ---------------- persistent LSTM: 64 blocks, weights in LDS, custom grid barrier ----------------
// block bid owns units u0=bid*8..+7 of BOTH layers (32 gate-rows each).
// Pipelined: iter t runs layer0 step t and layer1 step tau=t-1.
__global__ __launch_bounds__(256, 1) void k_lstm(const ushort* __restrict__ hlnb,
    const ushort* __restrict__ W0g, const ushort* __restrict__ W1g,
    const float* __restrict__ b0c, const float* __restrict__ b1c,
    ushort* __restrict__ h0b, ushort* __restrict__ h1b,
    ushort* __restrict__ h1hist, unsigned* __restrict__ cnt){
  __shared__ ushort Wlds0[32*808];   // rows padded 800->808 (16B-aligned, conflict-free)
  __shared__ ushort Wlds1[32*1032];  // 1024->1032
  __shared__ float pc0[32][33];
  __shared__ float pc1[32][33];

  const int tid  = threadIdx.x;
  const int bid  = blockIdx.x;
  const int u0   = bid << 3;
  const int wave = tid >> 6;
  const int lane = tid & 63;
  const int col  = lane & 15;
  const int kg   = lane >> 4;
  const int mh   = wave & 1;
  const int nh   = wave >> 1;
  const int arow = (mh<<4) + col;          // batch row for A-frag
  const int nlo  = (nh<<4) + col;          // local gate-row for B-frag

  // ---- load weights to LDS (once) ----
  for (int v = tid; v < 3200; v += 256){   // 32 rows x 100 vec8
    int r = v/100, c8 = v - r*100;
    int grow = ((r>>3)<<9) + u0 + (r&7);
    *(short8*)&Wlds0[r*808 + c8*8] = *(const short8*)(W0g + (size_t)grow*K0 + c8*8);
  }
  for (int v = tid; v < 4096; v += 256){   // 32 rows x 128 vec8
    int r = v>>7, c8 = v&127;
    int grow = ((r>>3)<<9) + u0 + (r&7);
    *(short8*)&Wlds1[r*1032 + c8*8] = *(const short8*)(W1g + (size_t)grow*K1 + c8*8);
  }
  const int bb = tid & 31;                 // batch owned in gate phase
  const int ul = tid >> 5;                 // unit owned (0..7)
  const int u  = u0 + ul;
  float bc0r[4], bc1r[4];
  #pragma unroll
  for (int g=0; g<4; g++){ bc0r[g] = b0c[(g<<9)+u]; bc1r[g] = b1c[(g<<9)+u]; }
  float c0r = 0.f, c1r = 0.f;
  const ushort* wb0 = &Wlds0[nlo*808];
  const ushort* wb1 = &Wlds1[nlo*1032];
  __syncthreads();

  for (int t = 0; t <= NT; ++t){
    const ushort* h0p = h0b + (size_t)((t-1)&1)*(BATCH*HID);
    f32x4 acc0 = {0.f,0.f,0.f,0.f};
    f32x4 acc1 = {0.f,0.f,0.f,0.f};
    if (t >= 1){                           // layer1, tau = t-1
      const ushort* h1p = h1b + (size_t)((t-2)&1)*(BATCH*HID);
      #pragma unroll
      for (int kt=0; kt<16; kt++){
        short8 a = *(const short8*)(h0p + arow*HID + kt*32 + kg*8);
        short8 b = *(const short8*)(wb1 + kt*32 + kg*8);
        acc1 = __builtin_amdgcn_mfma_f32_16x16x32_bf16(a, b, acc1, 0, 0, 0);
      }
      #pragma unroll
      for (int kt=0; kt<16; kt++){
        short8 a = *(const short8*)(h1p + arow*HID + kt*32 + kg*8);
        short8 b = *(const short8*)(wb1 + 512 + kt*32 + kg*8);
        acc1 = __builtin_amdgcn_mfma_f32_16x16x32_bf16(a, b, acc1, 0, 0, 0);
      }
    }
    if (t < NT){                           // layer0, step t
      const ushort* xt = hlnb + (size_t)t*BATCH*NFP;
      #pragma unroll
      for (int kt=0; kt<9; kt++){
        short8 a = *(const short8*)(xt + arow*NFP + kt*32 + kg*8);
        short8 b = *(const short8*)(wb0 + kt*32 + kg*8);
        acc0 = __builtin_amdgcn_mfma_f32_16x16x32_bf16(a, b, acc0, 0, 0, 0);
      }
      #pragma unroll
      for (int kt=0; kt<16; kt++){
        short8 a = *(const short8*)(h0p + arow*HID + kt*32 + kg*8);
        short8 b = *(const short8*)(wb0 + 288 + kt*32 + kg*8);
        acc0 = __builtin_amdgcn_mfma_f32_16x16x32_bf16(a, b, acc0, 0, 0, 0);
      }
    }
    // C layout: batch = mh*16 + kg*4 + j, gate-row = nlo
    if (t < NT){
      #pragma unroll
      for (int j=0;j<4;j++) pc0[(mh<<4)+(kg<<2)+j][nlo] = acc0[j];
    }
    if (t >= 1){
      #pragma unroll
      for (int j=0;j<4;j++) pc1[(mh<<4)+(kg<<2)+j][nlo] = acc1[j];
    }
    __syncthreads();
    // ---- gate phase: thread owns (bb, u) for both layers ----
    if (t < NT){
      float p0 = pc0[bb][0*8+ul] + bc0r[0];
      float p1 = pc0[bb][1*8+ul] + bc0r[1];
      float p2 = pc0[bb][2*8+ul] + bc0r[2];
      float p3 = pc0[bb][3*8+ul] + bc0r[3];
      float cn = sigm(p1)*c0r + sigm(p0)*tanhf(p2);
      float hn = sigm(p3)*tanhf(cn);
      c0r = cn;
      h0b[(size_t)(t&1)*(BATCH*HID) + bb*HID + u] = f2bf(hn);
    }
    if (t >= 1){
      float p0 = pc1[bb][0*8+ul] + bc1r[0];
      float p1 = pc1[bb][1*8+ul] + bc1r[1];
      float p2 = pc1[bb][2*8+ul] + bc1r[2];
      float p3 = pc1[bb][3*8+ul] + bc1r[3];
      float cn = sigm(p1)*c1r + sigm(p0)*tanhf(p2);
      float hn = sigm(p3)*tanhf(cn);
      c1r = cn;
      ushort hb = f2bf(hn);
      h1b[(size_t)((t-1)&1)*(BATCH*HID) + bb*HID + u] = hb;
      h1hist[(size_t)t*(BATCH*HID) + bb*HID + u] = hb;   // slot tau+1 = t
    }
    // ---- grid barrier (monotonic counter, precise wakeup) ----
    __syncthreads();
    if (tid == 0){
      __threadfence();
      __hip_atomic_fetch_add(cnt, 1u, __ATOMIC_RELEASE, __HIP_MEMORY_SCOPE_AGENT);
      unsigned target = (unsigned)(t+1) * NBLK;
      while (__hip_atomic_load(cnt, __ATOMIC_RELAXED, __HIP_MEMORY_SCOPE_AGENT) < target)
        __builtin_amdgcn_s_sleep(1);
      __threadfence();
    }
    __syncthreads();
  }
}

// ---------------- STFT for a tail chunk: frames t = tb0+tt, layout [b][f][36] ----------------
__global__ __launch_bounds__(256) void k_stft_chunk(const float* __restrict__ x, const float* __restrict__ tw,
                                                    float* __restrict__ spR, float* __restrict__ spI, int tb0){
  int tt = blockIdx.x;
  int b  = blockIdx.y;
  int t  = tb0 + tt;
  if (t < 0 || t >= NT){
    for (int f = threadIdx.x; f < NF; f += 256){
      size_t o = ((size_t)b*NF + f)*36 + tt;
      spR[o]=0.f; spI[o]=0.f;
    }
    return;
  }
  __shared__ float fr[NFFT], lc[NFFT], ls[NFFT];
  const float* xb = x + (size_t)b*LEN;
  for (int n = threadIdx.x; n < NFFT; n += 256){
    lc[n] = tw[n]; ls[n] = tw[512+n];
    int j = t*256 + n - 256;
    if (j < 0) j = -j;
    else if (j >= LEN) j = 2*LEN - 2 - j;
    fr[n] = xb[j] * (0.5f - 0.5f*tw[n]);
  }
  __syncthreads();
  for (int f = threadIdx.x; f < NF; f += 256){
    float ar = 0.f, ai = 0.f;
    int idx = 0;
    #pragma unroll 8
    for (int n = 0; n < NFFT; n++){
      float vv = fr[n];
      ar += vv*lc[idx];
      ai -= vv*ls[idx];
      idx = (idx + f) & 511;
    }
    size_t o = ((size_t)b*NF + f)*36 + tt;
    spR[o] = ar; spI[o] = ai;
  }
}

// ---------------- GEMM: C[M,N] = A_bf16[M,K]*Bm[N,K]^T + bias, tanh ----------------
__global__ __launch_bounds__(256) void k_gemm_tanh(const ushort* __restrict__ A, const float* __restrict__ Bm,
                                                   const float* __restrict__ bias,
                                                   float* __restrict__ C, int M, int N, int K){
  __shared__ float As[16][65];
  __shared__ float Bs[16][65];
  int bm = blockIdx.y*64, bn = blockIdx.x*64;
  int tx = threadIdx.x & 15, ty = threadIdx.x >> 4;
  float acc[4][4] = {};
  for (int k0=0; k0<K; k0+=16){
    for (int i=threadIdx.x; i<1024; i+=256){
      int r=i>>4, c=i&15;
      int kk=k0+c;
      As[c][r] = bf2f(A[(size_t)(bm+r)*K + kk]);
      int nn=bn+r;
      Bs[c][r] = (nn<N) ? Bm[(size_t)nn*K + kk] : 0.f;
    }
    __syncthreads();
    #pragma unroll
    for (int kk=0; kk<16; kk++){
      float a[4], bb[4];
      #pragma unroll
      for (int i=0;i<4;i++) a[i]=As[kk][ty*4+i];
      #pragma unroll
      for (int j=0;j<4;j++) bb[j]=Bs[kk][tx*4+j];
      #pragma unroll
      for (int i=0;i<4;i++)
        #pragma unroll
        for (int j=0;j<4;j++)
          acc[i][j] += a[i]*bb[j];
    }
    __syncthreads();
  }
  for (int i=0;i<4;i++){
    int m = bm + ty*4 + i;
    for (int j=0;j<4;j++){
      int n = bn + tx*4 + j;
      if (n < N)
        C[(size_t)m*N + n] = tanhf(acc[i][j] + bias[n]);
    }
  }
}

// ---------------- fused deep-filter + irfft + window + OLA(atomic) ----------------
__global__ __launch_bounds__(256) void k_ifused(const float* __restrict__ prch,
    const float* __restrict__ spR, const float* __restrict__ spI,
    const float* __restrict__ tw, float* __restrict__ out, int tb0){
  int tl = blockIdx.x >> 6;
  int b  = (blockIdx.x >> 1) & 31;
  int s  = blockIdx.x & 1;
  int tau = tb0 + 4 + tl;
  __shared__ float re[NF], im[NF], lc[NFFT], ls[NFFT];
  for (int i=threadIdx.x; i<NFFT; i+=256){ lc[i]=tw[i]; ls[i]=tw[512+i]; }
  const float* p = prch + ((size_t)tl*BATCH + b)*PROJN;
  for (int f=threadIdx.x; f<NF; f+=256){
    float ar=0.f, ai=0.f;
    size_t so = ((size_t)b*NF + f)*36;
    #pragma unroll
    for (int d=0; d<5; d++){
      int ts = tb0 + tl + d;
      if (ts >= 0){
        float sr=spR[so + tl + d], si=spI[so + tl + d];
        float cr=p[d*514 + s*257 + f];
        float ci=p[2570 + d*514 + s*257 + f];
        ar += sr*cr - si*ci;
        ai += sr*ci + si*cr;
      }
    }
    re[f]=ar; im[f]=ai;
  }
  __syncthreads();
  float* ob = out + (size_t)(b*2+s)*LEN;
  for (int n=threadIdx.x; n<NFFT; n+=256){
    float acc = re[0] + ((n&1) ? -re[256] : re[256]);
    int idx = n;
    #pragma unroll 8
    for (int k=1; k<256; k++){
      acc += 2.f*(re[k]*lc[idx] - im[k]*ls[idx]);
      idx = (idx + n) & 511;
    }
    int pos = tau*256 - 256 + n;
    if (pos >= 0 && pos < LEN)
      atomicAdd(ob + pos, acc * (1.0f/512.0f) * (0.5f - 0.5f*lc[n]));
  }
}

// ---------------- normalize by wsq ----------------
__global__ __launch_bounds__(256) void k_norm(float* __restrict__ out, const float* __restrict__ tw, int n){
  for (int i = blockIdx.x*256 + threadIdx.x; i < n; i += gridDim.x*256){
    int m = (i % LEN) & 255;
    float cm = tw[m];
    float w1 = 0.5f - 0.5f*cm;
    float w2 = 0.5f + 0.5f*cm;
    out[i] = out[i] / (w1*w1 + w2*w2);
  }
}

extern "C" void kernel_launch(void* const* d_in, const int* in_sizes, int n_in,
                              void* d_out, int out_size, void* d_ws, size_t ws_size,
                              hipStream_t stream){
  const float* x     = (const float*)d_in[0];
  const float* ln_g  = (const float*)d_in[1];
  const float* ln_b  = (const float*)d_in[2];
  const float* Wih0  = (const float*)d_in[3];
  const float* Whh0  = (const float*)d_in[4];
  const float* bih0  = (const float*)d_in[5];
  const float* bhh0  = (const float*)d_in[6];
  const float* Wih1  = (const float*)d_in[7];
  const float* Whh1  = (const float*)d_in[8];
  const float* bih1  = (const float*)d_in[9];
  const float* bhh1  = (const float*)d_in[10];
  const float* projW = (const float*)d_in[11];
  const float* projb = (const float*)d_in[12];

  char* base = (char*)d_ws;
  size_t off = 0;
  auto carve = [&](size_t bytes)->char*{
    char* p = base + off;
    off += (bytes + 255) & ~(size_t)255;
    return p;
  };
  float*  tw     = (float*) carve(1024*4);
  ushort* hlnb   = (ushort*)carve((size_t)NT*BATCH*NFP*2);
  ushort* W0     = (ushort*)carve((size_t)2048*K0*2);
  ushort* W1     = (ushort*)carve((size_t)2048*K1*2);
  float*  b0c    = (float*) carve(2048*4);
  float*  b1c    = (float*) carve(2048*4);
  ushort* h0b    = (ushort*)carve((size_t)2*BATCH*HID*2);   // 65536B
  ushort* h1b    = (ushort*)carve((size_t)2*BATCH*HID*2);   // 65536B
  unsigned* cnt  = (unsigned*)carve(256);
  ushort* h1hist = (ushort*)carve((size_t)(NT+1)*BATCH*HID*2);
  float*  spR    = (float*) carve((size_t)BATCH*NF*36*4);
  float*  spI    = (float*) carve((size_t)BATCH*NF*36*4);
  float*  prch   = (float*) carve((size_t)TC*BATCH*PROJN*4);

  // zero region: h0b, h1b, cnt contiguous
  int nzInts = (int)((65536 + 65536 + 256) / 4);

  k_init<<<512, 256, 0, stream>>>(tw, (int*)h0b, nzInts);
  k_zero<<<2048, 256, 0, stream>>>((float*)d_out, out_size);
  k_prep<<<4096, 256, 0, stream>>>(Wih0, Whh0, bih0, bhh0, Wih1, Whh1, bih1, bhh1,
                                   W0, W1, b0c, b1c);
  k_stftln<<<BATCH*NT, 256, 0, stream>>>(x, tw, ln_g, ln_b, hlnb);

  {
    void* args[] = { (void*)&hlnb, (void*)&W0, (void*)&W1, (void*)&b0c, (void*)&b1c,
                     (void*)&h0b, (void*)&h1b, (void*)&h1hist, (void*)&cnt };
    hipLaunchCooperativeKernel(reinterpret_cast<void*>(k_lstm), dim3(NBLK), dim3(256),
                               args, 0, stream);
  }

  for (int c = 0; c < NCHUNK; ++c){
    int tb0 = c*TC - 4;
    int tcc = (c == NCHUNK-1) ? (NT - c*TC) : TC;
    k_stft_chunk<<<dim3(36, BATCH), 256, 0, stream>>>(x, tw, spR, spI, tb0);
    dim3 gp((PROJN+63)/64, (tcc*BATCH)/64);
    k_gemm_tanh<<<gp, 256, 0, stream>>>(h1hist + ((size_t)(c*TC)+1)*BATCH*HID, projW, projb,
                                        prch, tcc*BATCH, PROJN, HID);
    k_ifused<<<tcc*64, 256, 0, stream>>>(prch, spR, spI, tw, (float*)d_out, tb0);
  }

  k_norm<<<2048, 256, 0, stream>>>((float*)d_out, tw, out_size);
}

// Round 5
// 12050.933 us; speedup vs baseline: 5.2137x; 1.3469x over previous
//
#include <hip/hip_runtime.h>
#include <hip/hip_cooperative_groups.h>
#include <math.h>

#define BATCH 32
#define LEN   160000
#define NFFT  512
#define NT    626
#define NF    257
#define NFP   288          // NF padded to 9*32
#define HID   512
#define PROJN 5140
#define TC    32
#define NCHUNK 20
#define K0    800          // NFP + HID
#define K1    1024         // HID + HID
#define NBLK  64           // LSTM grid

typedef unsigned short ushort;
typedef __attribute__((ext_vector_type(8))) short short8;
typedef __attribute__((ext_vector_type(4))) float f32x4;

__device__ __forceinline__ float sigm(float x){ return 1.0f/(1.0f+expf(-x)); }
__device__ __forceinline__ ushort f2bf(float f){
  union{float f;unsigned u;} v; v.f=f;
  unsigned r = v.u + 0x7fffu + ((v.u>>16)&1u);
  return (ushort)(r>>16);
}
__device__ __forceinline__ float bf2f(ushort h){
  union{unsigned u;float f;} v; v.u = ((unsigned)h)<<16;
  return v.f;
}

// ---------------- init: twiddles + zero int region ----------------
__global__ __launch_bounds__(256) void k_init(float* tw, int* zr, int nz){
  int i = blockIdx.x*256 + threadIdx.x;
  if (i < 512){
    float ang = 6.28318530717958647692f * (float)i / 512.0f;
    tw[i]     = cosf(ang);
    tw[512+i] = sinf(ang);
  }
  for (int j = i; j < nz; j += gridDim.x*256) zr[j] = 0;
}

__global__ __launch_bounds__(256) void k_zero(float* p, int n){
  for (int i = blockIdx.x*256 + threadIdx.x; i < n; i += gridDim.x*256) p[i] = 0.f;
}

// ---------------- prep: bf16 weight concat + combined biases + bf16 projW ----------------
__global__ __launch_bounds__(256) void k_prep(const float* __restrict__ Wih0, const float* __restrict__ Whh0,
                                              const float* __restrict__ bih0, const float* __restrict__ bhh0,
                                              const float* __restrict__ Wih1, const float* __restrict__ Whh1,
                                              const float* __restrict__ bih1, const float* __restrict__ bhh1,
                                              const float* __restrict__ projW,
                                              ushort* __restrict__ W0, ushort* __restrict__ W1,
                                              float* __restrict__ b0c, float* __restrict__ b1c,
                                              ushort* __restrict__ projWb){
  const int n0 = 2048*K0, n1 = 2048*K1, n2 = PROJN*HID;
  for (int i = blockIdx.x*256 + threadIdx.x; i < n0 + n1 + 4096 + n2; i += gridDim.x*256){
    if (i < n0){
      int r = i / K0, c = i - r*K0;
      float v = (c < 257) ? Wih0[(size_t)r*257 + c] : (c < NFP ? 0.f : Whh0[(size_t)r*512 + (c-NFP)]);
      W0[i] = f2bf(v);
    } else if (i < n0 + n1){
      int j = i - n0;
      int r = j / K1, c = j - r*K1;
      float v = (c < 512) ? Wih1[(size_t)r*512 + c] : Whh1[(size_t)r*512 + (c-512)];
      W1[j] = f2bf(v);
    } else if (i < n0 + n1 + 4096){
      int j = i - n0 - n1;
      if (j < 2048) b0c[j] = bih0[j] + bhh0[j];
      else          b1c[j-2048] = bih1[j-2048] + bhh1[j-2048];
    } else {
      int j = i - n0 - n1 - 4096;
      projWb[j] = f2bf(projW[j]);     // same row-major [PROJN][512]
    }
  }
}

// ---------------- fused STFT + mag^0.5 + LayerNorm -> bf16 padded [t][b][NFP] ----------------
// DFT via per-thread twiddle rotation (no LDS twiddle reads; fr[] reads are broadcast).
__global__ __launch_bounds__(256) void k_stftln(const float* __restrict__ x, const float* __restrict__ tw,
                                                const float* __restrict__ g, const float* __restrict__ be,
                                                ushort* __restrict__ hlnb){
  int b = blockIdx.x / NT;
  int t = blockIdx.x % NT;
  __shared__ float fr[NFFT], mg[NF];
  __shared__ float red[16];
  const float* xb = x + (size_t)b*LEN;
  for (int n = threadIdx.x; n < NFFT; n += 256){
    int j = t*256 + n - 256;
    if (j < 0) j = -j;
    else if (j >= LEN) j = 2*LEN - 2 - j;
    fr[n] = xb[j] * (0.5f - 0.5f*tw[n]);
  }
  __syncthreads();
  float v=0.f, v2=0.f;
  for (int f = threadIdx.x; f < NF; f += 256){
    float c1 = tw[f], s1 = tw[512+f];
    float cr = 1.f, si = 0.f;
    float ar = 0.f, ai = 0.f;
    #pragma unroll 8
    for (int n = 0; n < NFFT; n++){
      float vv = fr[n];
      ar += vv*cr;
      ai -= vv*si;
      float cn = cr*c1 - si*s1;
      si = cr*s1 + si*c1;
      cr = cn;
    }
    float m = sqrtf(sqrtf(ar*ar + ai*ai));
    mg[f]=m; v+=m; v2+=m*m;
  }
  for (int off=32; off; off>>=1){ v += __shfl_down(v,off); v2 += __shfl_down(v2,off); }
  int w = threadIdx.x >> 6;
  if ((threadIdx.x & 63)==0){ red[w]=v; red[8+w]=v2; }
  __syncthreads();
  if (threadIdx.x==0){
    float s  = red[0]+red[1]+red[2]+red[3];
    float s2 = red[8]+red[9]+red[10]+red[11];
    float mu = s/(float)NF;
    red[4]=mu;
    red[5]=rsqrtf(s2/(float)NF - mu*mu + 1e-5f);
  }
  __syncthreads();
  float mu=red[4], rs=red[5];
  size_t ob = ((size_t)t*BATCH + b)*NFP;
  for (int f=threadIdx.x; f<NFP; f+=256){
    float val = 0.f;
    if (f < NF) val = (mg[f]-mu)*rs*g[f] + be[f];
    hlnb[ob+f] = f2bf(val);
  }
}

// ---------------- persistent LSTM: 64 blocks, weights in LDS, lean grid barrier ----------------
__global__ __launch_bounds__(256, 1) void k_lstm(const ushort* __restrict__ hlnb,
    const ushort* __restrict__ W0g, const ushort* __restrict__ W1g,
    const float* __restrict__ b0c, const float* __restrict__ b1c,
    ushort* __restrict__ h0b, ushort* __restrict__ h1b,
    ushort* __restrict__ h1hist, unsigned* __restrict__ cnt){
  __shared__ ushort Wlds0[32*808];   // rows padded 800->808
  __shared__ ushort Wlds1[32*1032];  // 1024->1032
  __shared__ float pc0[32][33];
  __shared__ float pc1[32][33];

  const int tid  = threadIdx.x;
  const int bid  = blockIdx.x;
  const int u0   = bid << 3;
  const int wave = tid >> 6;
  const int lane = tid & 63;
  const int col  = lane & 15;
  const int kg   = lane >> 4;
  const int mh   = wave & 1;
  const int nh   = wave >> 1;
  const int arow = (mh<<4) + col;          // batch row for A-frag
  const int nlo  = (nh<<4) + col;          // local gate-row for B-frag

  for (int v = tid; v < 3200; v += 256){
    int r = v/100, c8 = v - r*100;
    int grow = ((r>>3)<<9) + u0 + (r&7);
    *(short8*)&Wlds0[r*808 + c8*8] = *(const short8*)(W0g + (size_t)grow*K0 + c8*8);
  }
  for (int v = tid; v < 4096; v += 256){
    int r = v>>7, c8 = v&127;
    int grow = ((r>>3)<<9) + u0 + (r&7);
    *(short8*)&Wlds1[r*1032 + c8*8] = *(const short8*)(W1g + (size_t)grow*K1 + c8*8);
  }
  const int bb = tid & 31;
  const int ul = tid >> 5;
  const int u  = u0 + ul;
  float bc0r[4], bc1r[4];
  #pragma unroll
  for (int g=0; g<4; g++){ bc0r[g] = b0c[(g<<9)+u]; bc1r[g] = b1c[(g<<9)+u]; }
  float c0r = 0.f, c1r = 0.f;
  const ushort* wb0 = &Wlds0[nlo*808];
  const ushort* wb1 = &Wlds1[nlo*1032];
  __syncthreads();

  // prefetch x-part of layer0 for t=0
  f32x4 acc0x = {0.f,0.f,0.f,0.f};
  {
    const ushort* xt = hlnb;
    #pragma unroll
    for (int kt=0; kt<9; kt++){
      short8 a = *(const short8*)(xt + arow*NFP + kt*32 + kg*8);
      short8 b = *(const short8*)(wb0 + kt*32 + kg*8);
      acc0x = __builtin_amdgcn_mfma_f32_16x16x32_bf16(a, b, acc0x, 0, 0, 0);
    }
  }

  for (int t = 0; t <= NT; ++t){
    const ushort* h0p = h0b + (size_t)((t-1)&1)*(BATCH*HID);
    f32x4 acc0 = acc0x;
    f32x4 acc1 = {0.f,0.f,0.f,0.f};
    if (t >= 1){                           // layer1, tau = t-1
      const ushort* h1p = h1b + (size_t)((t-2)&1)*(BATCH*HID);
      #pragma unroll
      for (int kt=0; kt<16; kt++){
        short8 a = *(const short8*)(h0p + arow*HID + kt*32 + kg*8);
        short8 b = *(const short8*)(wb1 + kt*32 + kg*8);
        acc1 = __builtin_amdgcn_mfma_f32_16x16x32_bf16(a, b, acc1, 0, 0, 0);
      }
      #pragma unroll
      for (int kt=0; kt<16; kt++){
        short8 a = *(const short8*)(h1p + arow*HID + kt*32 + kg*8);
        short8 b = *(const short8*)(wb1 + 512 + kt*32 + kg*8);
        acc1 = __builtin_amdgcn_mfma_f32_16x16x32_bf16(a, b, acc1, 0, 0, 0);
      }
    }
    if (t < NT){                           // layer0 h-part, step t
      #pragma unroll
      for (int kt=0; kt<16; kt++){
        short8 a = *(const short8*)(h0p + arow*HID + kt*32 + kg*8);
        short8 b = *(const short8*)(wb0 + 288 + kt*32 + kg*8);
        acc0 = __builtin_amdgcn_mfma_f32_16x16x32_bf16(a, b, acc0, 0, 0, 0);
      }
    }
    if (t < NT){
      #pragma unroll
      for (int j=0;j<4;j++) pc0[(mh<<4)+(kg<<2)+j][nlo] = acc0[j];
    }
    if (t >= 1){
      #pragma unroll
      for (int j=0;j<4;j++) pc1[(mh<<4)+(kg<<2)+j][nlo] = acc1[j];
    }
    __syncthreads();
    // ---- gate phase ----
    if (t < NT){
      float p0 = pc0[bb][0*8+ul] + bc0r[0];
      float p1 = pc0[bb][1*8+ul] + bc0r[1];
      float p2 = pc0[bb][2*8+ul] + bc0r[2];
      float p3 = pc0[bb][3*8+ul] + bc0r[3];
      float cn = sigm(p1)*c0r + sigm(p0)*tanhf(p2);
      float hn = sigm(p3)*tanhf(cn);
      c0r = cn;
      __builtin_nontemporal_store(f2bf(hn), h0b + (size_t)(t&1)*(BATCH*HID) + bb*HID + u);
    }
    if (t >= 1){
      float p0 = pc1[bb][0*8+ul] + bc1r[0];
      float p1 = pc1[bb][1*8+ul] + bc1r[1];
      float p2 = pc1[bb][2*8+ul] + bc1r[2];
      float p3 = pc1[bb][3*8+ul] + bc1r[3];
      float cn = sigm(p1)*c1r + sigm(p0)*tanhf(p2);
      float hn = sigm(p3)*tanhf(cn);
      c1r = cn;
      ushort hb = f2bf(hn);
      __builtin_nontemporal_store(hb, h1b + (size_t)((t-1)&1)*(BATCH*HID) + bb*HID + u);
      __builtin_nontemporal_store(hb, h1hist + (size_t)t*(BATCH*HID) + bb*HID + u);
    }
    __syncthreads();                       // all h writes drained (vmcnt0 per wave)
    if (tid == 0)                          // arrive: RELEASE (one L2 writeback)
      __hip_atomic_fetch_add(cnt, 1u, __ATOMIC_RELEASE, __HIP_MEMORY_SCOPE_AGENT);
    // overlap: h-independent x-part of layer0 for step t+1
    acc0x = f32x4{0.f,0.f,0.f,0.f};
    if (t+1 < NT){
      const ushort* xt = hlnb + (size_t)(t+1)*BATCH*NFP;
      #pragma unroll
      for (int kt=0; kt<9; kt++){
        short8 a = *(const short8*)(xt + arow*NFP + kt*32 + kg*8);
        short8 b = *(const short8*)(wb0 + kt*32 + kg*8);
        acc0x = __builtin_amdgcn_mfma_f32_16x16x32_bf16(a, b, acc0x, 0, 0, 0);
      }
    }
    if (tid == 0){
      unsigned target = (unsigned)(t+1) * NBLK;
      while (__hip_atomic_load(cnt, __ATOMIC_RELAXED, __HIP_MEMORY_SCOPE_AGENT) < target)
        __builtin_amdgcn_s_sleep(1);
      (void)__hip_atomic_load(cnt, __ATOMIC_ACQUIRE, __HIP_MEMORY_SCOPE_AGENT);  // one L2 inv
    }
    __syncthreads();
  }
}

// ---------------- STFT for a tail chunk (rotation DFT) ----------------
__global__ __launch_bounds__(256) void k_stft_chunk(const float* __restrict__ x, const float* __restrict__ tw,
                                                    float* __restrict__ spR, float* __restrict__ spI, int tb0){
  int tt = blockIdx.x;
  int b  = blockIdx.y;
  int t  = tb0 + tt;
  if (t < 0 || t >= NT){
    for (int f = threadIdx.x; f < NF; f += 256){
      size_t o = ((size_t)b*NF + f)*36 + tt;
      spR[o]=0.f; spI[o]=0.f;
    }
    return;
  }
  __shared__ float fr[NFFT];
  const float* xb = x + (size_t)b*LEN;
  for (int n = threadIdx.x; n < NFFT; n += 256){
    int j = t*256 + n - 256;
    if (j < 0) j = -j;
    else if (j >= LEN) j = 2*LEN - 2 - j;
    fr[n] = xb[j] * (0.5f - 0.5f*tw[n]);
  }
  __syncthreads();
  for (int f = threadIdx.x; f < NF; f += 256){
    float c1 = tw[f], s1 = tw[512+f];
    float cr = 1.f, si = 0.f;
    float ar = 0.f, ai = 0.f;
    #pragma unroll 8
    for (int n = 0; n < NFFT; n++){
      float vv = fr[n];
      ar += vv*cr;
      ai -= vv*si;
      float cn = cr*c1 - si*s1;
      si = cr*s1 + si*c1;
      cr = cn;
    }
    size_t o = ((size_t)b*NF + f)*36 + tt;
    spR[o] = ar; spI[o] = ai;
  }
}

// ---------------- MFMA GEMM: C[M,N] = A_bf16[M,512] * Bb_bf16[N,512]^T + bias, tanh ----------------
__global__ __launch_bounds__(256) void k_gemm_mfma(const ushort* __restrict__ A, const ushort* __restrict__ Bb,
                                                   const float* __restrict__ bias,
                                                   float* __restrict__ C, int M, int N){
  int bm = blockIdx.y*64, bn = blockIdx.x*64;
  int wave = threadIdx.x >> 6, lane = threadIdx.x & 63;
  int wm = wave >> 1, wn = wave & 1;
  int col = lane & 15, kg = lane >> 4;
  f32x4 acc00={0.f,0.f,0.f,0.f}, acc01=acc00, acc10=acc00, acc11=acc00;
  const ushort* Ap = A + (size_t)(bm + wm*32)*512;
  int nr0 = bn + wn*32 + col;
  int nr1 = nr0 + 16;
  const ushort* Bp0 = Bb + (size_t)((nr0<N)?nr0:0)*512;
  const ushort* Bp1 = Bb + (size_t)((nr1<N)?nr1:0)*512;
  #pragma unroll 4
  for (int k0=0; k0<512; k0+=32){
    short8 a0 = *(const short8*)(Ap + (size_t)col*512 + k0 + kg*8);
    short8 a1 = *(const short8*)(Ap + (size_t)(16+col)*512 + k0 + kg*8);
    short8 b0 = *(const short8*)(Bp0 + k0 + kg*8);
    short8 b1 = *(const short8*)(Bp1 + k0 + kg*8);
    acc00 = __builtin_amdgcn_mfma_f32_16x16x32_bf16(a0, b0, acc00, 0, 0, 0);
    acc01 = __builtin_amdgcn_mfma_f32_16x16x32_bf16(a0, b1, acc01, 0, 0, 0);
    acc10 = __builtin_amdgcn_mfma_f32_16x16x32_bf16(a1, b0, acc10, 0, 0, 0);
    acc11 = __builtin_amdgcn_mfma_f32_16x16x32_bf16(a1, b1, acc11, 0, 0, 0);
  }
  // D element j: A-row = kg*4+j (within 16), B-row(col of C) = col
  #define STORE_ACC(ACC, MI, NI) { \
    int n = bn + wn*32 + (NI)*16 + col; \
    if (n < N){ \
      float bv = bias[n]; \
      _Pragma("unroll") \
      for (int j=0;j<4;j++){ \
        int m = bm + wm*32 + (MI)*16 + kg*4 + j; \
        C[(size_t)m*N + n] = tanhf(ACC[j] + bv); \
      } \
    } }
  STORE_ACC(acc00, 0, 0)
  STORE_ACC(acc01, 0, 1)
  STORE_ACC(acc10, 1, 0)
  STORE_ACC(acc11, 1, 1)
  #undef STORE_ACC
}

// ---------------- fused deep-filter + irfft(rotation) + window + OLA(atomic) ----------------
__global__ __launch_bounds__(256) void k_ifused(const float* __restrict__ prch,
    const float* __restrict__ spR, const float* __restrict__ spI,
    const float* __restrict__ tw, float* __restrict__ out, int tb0){
  int tl = blockIdx.x >> 6;
  int b  = (blockIdx.x >> 1) & 31;
  int s  = blockIdx.x & 1;
  int tau = tb0 + 4 + tl;
  __shared__ float re[NF], im[NF];
  const float* p = prch + ((size_t)tl*BATCH + b)*PROJN;
  for (int f=threadIdx.x; f<NF; f+=256){
    float ar=0.f, ai=0.f;
    size_t so = ((size_t)b*NF + f)*36;
    #pragma unroll
    for (int d=0; d<5; d++){
      int ts = tb0 + tl + d;
      if (ts >= 0){
        float sr=spR[so + tl + d], si=spI[so + tl + d];
        float cr=p[d*514 + s*257 + f];
        float ci=p[2570 + d*514 + s*257 + f];
        ar += sr*cr - si*ci;
        ai += sr*ci + si*cr;
      }
    }
    re[f]=ar; im[f]=ai;
  }
  __syncthreads();
  float* ob = out + (size_t)(b*2+s)*LEN;
  for (int n=threadIdx.x; n<NFFT; n+=256){
    float c1 = tw[n], s1 = tw[512+n];
    float acc = re[0] + ((n&1) ? -re[256] : re[256]);
    float cr = c1, si = s1;
    #pragma unroll 8
    for (int k=1; k<256; k++){
      acc += 2.f*(re[k]*cr - im[k]*si);
      float cn = cr*c1 - si*s1;
      si = cr*s1 + si*c1;
      cr = cn;
    }
    int pos = tau*256 - 256 + n;
    if (pos >= 0 && pos < LEN)
      atomicAdd(ob + pos, acc * (1.0f/512.0f) * (0.5f - 0.5f*c1));
  }
}

// ---------------- normalize by wsq ----------------
__global__ __launch_bounds__(256) void k_norm(float* __restrict__ out, const float* __restrict__ tw, int n){
  for (int i = blockIdx.x*256 + threadIdx.x; i < n; i += gridDim.x*256){
    int m = (i % LEN) & 255;
    float cm = tw[m];
    float w1 = 0.5f - 0.5f*cm;
    float w2 = 0.5f + 0.5f*cm;
    out[i] = out[i] / (w1*w1 + w2*w2);
  }
}

extern "C" void kernel_launch(void* const* d_in, const int* in_sizes, int n_in,
                              void* d_out, int out_size, void* d_ws, size_t ws_size,
                              hipStream_t stream){
  const float* x     = (const float*)d_in[0];
  const float* ln_g  = (const float*)d_in[1];
  const float* ln_b  = (const float*)d_in[2];
  const float* Wih0  = (const float*)d_in[3];
  const float* Whh0  = (const float*)d_in[4];
  const float* bih0  = (const float*)d_in[5];
  const float* bhh0  = (const float*)d_in[6];
  const float* Wih1  = (const float*)d_in[7];
  const float* Whh1  = (const float*)d_in[8];
  const float* bih1  = (const float*)d_in[9];
  const float* bhh1  = (const float*)d_in[10];
  const float* projW = (const float*)d_in[11];
  const float* projb = (const float*)d_in[12];

  char* base = (char*)d_ws;
  size_t off = 0;
  auto carve = [&](size_t bytes)->char*{
    char* p = base + off;
    off += (bytes + 255) & ~(size_t)255;
    return p;
  };
  float*  tw     = (float*) carve(1024*4);
  ushort* hlnb   = (ushort*)carve((size_t)NT*BATCH*NFP*2);
  ushort* W0     = (ushort*)carve((size_t)2048*K0*2);
  ushort* W1     = (ushort*)carve((size_t)2048*K1*2);
  float*  b0c    = (float*) carve(2048*4);
  float*  b1c    = (float*) carve(2048*4);
  ushort* projWb = (ushort*)carve((size_t)PROJN*HID*2);
  ushort* h0b    = (ushort*)carve((size_t)2*BATCH*HID*2);   // 65536B
  ushort* h1b    = (ushort*)carve((size_t)2*BATCH*HID*2);   // 65536B
  unsigned* cnt  = (unsigned*)carve(256);
  ushort* h1hist = (ushort*)carve((size_t)(NT+1)*BATCH*HID*2);
  float*  spR    = (float*) carve((size_t)BATCH*NF*36*4);
  float*  spI    = (float*) carve((size_t)BATCH*NF*36*4);
  float*  prch   = (float*) carve((size_t)TC*BATCH*PROJN*4);

  int nzInts = (int)((65536 + 65536 + 256) / 4);   // h0b, h1b, cnt contiguous

  k_init<<<512, 256, 0, stream>>>(tw, (int*)h0b, nzInts);
  k_zero<<<2048, 256, 0, stream>>>((float*)d_out, out_size);
  k_prep<<<4096, 256, 0, stream>>>(Wih0, Whh0, bih0, bhh0, Wih1, Whh1, bih1, bhh1,
                                   projW, W0, W1, b0c, b1c, projWb);
  k_stftln<<<BATCH*NT, 256, 0, stream>>>(x, tw, ln_g, ln_b, hlnb);

  {
    void* args[] = { (void*)&hlnb, (void*)&W0, (void*)&W1, (void*)&b0c, (void*)&b1c,
                     (void*)&h0b, (void*)&h1b, (void*)&h1hist, (void*)&cnt };
    hipLaunchCooperativeKernel(reinterpret_cast<void*>(k_lstm), dim3(NBLK), dim3(256),
                               args, 0, stream);
  }

  for (int c = 0; c < NCHUNK; ++c){
    int tb0 = c*TC - 4;
    int tcc = (c == NCHUNK-1) ? (NT - c*TC) : TC;
    k_stft_chunk<<<dim3(36, BATCH), 256, 0, stream>>>(x, tw, spR, spI, tb0);
    dim3 gp((PROJN+63)/64, (tcc*BATCH)/64);
    k_gemm_mfma<<<gp, 256, 0, stream>>>(h1hist + ((size_t)(c*TC)+1)*BATCH*HID, projWb, projb,
                                        prch, tcc*BATCH, PROJN);
    k_ifused<<<tcc*64, 256, 0, stream>>>(prch, spR, spI, tw, (float*)d_out, tb0);
  }

  k_norm<<<2048, 256, 0, stream>>>((float*)d_out, tw, out_size);
}

// Round 6
// 11946.848 us; speedup vs baseline: 5.2591x; 1.0087x over previous
//
#include <hip/hip_runtime.h>
#include <hip/hip_cooperative_groups.h>
#include <math.h>

#define BATCH 32
#define LEN   160000
#define NFFT  512
#define NT    626
#define NF    257
#define NFP   288          // NF padded to 9*32
#define HID   512
#define PROJN 5140
#define TC    32
#define NCHUNK 20
#define K0    800          // NFP + HID
#define K1    1024         // HID + HID
#define NBLK  64           // LSTM grid

typedef unsigned short ushort;
typedef __attribute__((ext_vector_type(8))) short short8;
typedef __attribute__((ext_vector_type(4))) float f32x4;

__device__ __forceinline__ float sigm(float x){ return 1.0f/(1.0f+expf(-x)); }
__device__ __forceinline__ ushort f2bf(float f){
  union{float f;unsigned u;} v; v.f=f;
  unsigned r = v.u + 0x7fffu + ((v.u>>16)&1u);
  return (ushort)(r>>16);
}
__device__ __forceinline__ float bf2f(ushort h){
  union{unsigned u;float f;} v; v.u = ((unsigned)h)<<16;
  return v.f;
}

// ---------------- init: twiddles + zero int region ----------------
__global__ __launch_bounds__(256) void k_init(float* tw, int* zr, int nz){
  int i = blockIdx.x*256 + threadIdx.x;
  if (i < 512){
    float ang = 6.28318530717958647692f * (float)i / 512.0f;
    tw[i]     = cosf(ang);
    tw[512+i] = sinf(ang);
  }
  for (int j = i; j < nz; j += gridDim.x*256) zr[j] = 0;
}

__global__ __launch_bounds__(256) void k_zero(float* p, int n){
  for (int i = blockIdx.x*256 + threadIdx.x; i < n; i += gridDim.x*256) p[i] = 0.f;
}

// ---------------- prep: bf16 weight concat + combined biases + bf16 projW ----------------
__global__ __launch_bounds__(256) void k_prep(const float* __restrict__ Wih0, const float* __restrict__ Whh0,
                                              const float* __restrict__ bih0, const float* __restrict__ bhh0,
                                              const float* __restrict__ Wih1, const float* __restrict__ Whh1,
                                              const float* __restrict__ bih1, const float* __restrict__ bhh1,
                                              const float* __restrict__ projW,
                                              ushort* __restrict__ W0, ushort* __restrict__ W1,
                                              float* __restrict__ b0c, float* __restrict__ b1c,
                                              ushort* __restrict__ projWb){
  const int n0 = 2048*K0, n1 = 2048*K1, n2 = PROJN*HID;
  for (int i = blockIdx.x*256 + threadIdx.x; i < n0 + n1 + 4096 + n2; i += gridDim.x*256){
    if (i < n0){
      int r = i / K0, c = i - r*K0;
      float v = (c < 257) ? Wih0[(size_t)r*257 + c] : (c < NFP ? 0.f : Whh0[(size_t)r*512 + (c-NFP)]);
      W0[i] = f2bf(v);
    } else if (i < n0 + n1){
      int j = i - n0;
      int r = j / K1, c = j - r*K1;
      float v = (c < 512) ? Wih1[(size_t)r*512 + c] : Whh1[(size_t)r*512 + (c-512)];
      W1[j] = f2bf(v);
    } else if (i < n0 + n1 + 4096){
      int j = i - n0 - n1;
      if (j < 2048) b0c[j] = bih0[j] + bhh0[j];
      else          b1c[j-2048] = bih1[j-2048] + bhh1[j-2048];
    } else {
      int j = i - n0 - n1 - 4096;
      projWb[j] = f2bf(projW[j]);     // same row-major [PROJN][512]
    }
  }
}

// ---------------- fused STFT + mag^0.5 + LayerNorm -> bf16 padded [t][b][NFP] ----------------
__global__ __launch_bounds__(256) void k_stftln(const float* __restrict__ x, const float* __restrict__ tw,
                                                const float* __restrict__ g, const float* __restrict__ be,
                                                ushort* __restrict__ hlnb){
  int b = blockIdx.x / NT;
  int t = blockIdx.x % NT;
  __shared__ float fr[NFFT], mg[NF];
  __shared__ float red[16];
  const float* xb = x + (size_t)b*LEN;
  for (int n = threadIdx.x; n < NFFT; n += 256){
    int j = t*256 + n - 256;
    if (j < 0) j = -j;
    else if (j >= LEN) j = 2*LEN - 2 - j;
    fr[n] = xb[j] * (0.5f - 0.5f*tw[n]);
  }
  __syncthreads();
  float v=0.f, v2=0.f;
  for (int f = threadIdx.x; f < NF; f += 256){
    float c1 = tw[f], s1 = tw[512+f];
    float cr = 1.f, si = 0.f;
    float ar = 0.f, ai = 0.f;
    #pragma unroll 8
    for (int n = 0; n < NFFT; n++){
      float vv = fr[n];
      ar += vv*cr;
      ai -= vv*si;
      float cn = cr*c1 - si*s1;
      si = cr*s1 + si*c1;
      cr = cn;
    }
    float m = sqrtf(sqrtf(ar*ar + ai*ai));
    mg[f]=m; v+=m; v2+=m*m;
  }
  for (int off=32; off; off>>=1){ v += __shfl_down(v,off); v2 += __shfl_down(v2,off); }
  int w = threadIdx.x >> 6;
  if ((threadIdx.x & 63)==0){ red[w]=v; red[8+w]=v2; }
  __syncthreads();
  if (threadIdx.x==0){
    float s  = red[0]+red[1]+red[2]+red[3];
    float s2 = red[8]+red[9]+red[10]+red[11];
    float mu = s/(float)NF;
    red[4]=mu;
    red[5]=rsqrtf(s2/(float)NF - mu*mu + 1e-5f);
  }
  __syncthreads();
  float mu=red[4], rs=red[5];
  size_t ob = ((size_t)t*BATCH + b)*NFP;
  for (int f=threadIdx.x; f<NFP; f+=256){
    float val = 0.f;
    if (f < NF) val = (mg[f]-mu)*rs*g[f] + be[f];
    hlnb[ob+f] = f2bf(val);
  }
}

// ---------------- persistent LSTM: 64 blocks, weights in LDS, store/poll barrier ----------------
// flags: NBLK slots, 128B apart (32 uints). Arrival = RELEASE store of t+1 to own slot.
// Wait = wave0 gathers all 64 flags (one lane each), __all >= t+1, then one ACQUIRE load.
__global__ __launch_bounds__(256, 1) void k_lstm(const ushort* __restrict__ hlnb,
    const ushort* __restrict__ W0g, const ushort* __restrict__ W1g,
    const float* __restrict__ b0c, const float* __restrict__ b1c,
    ushort* __restrict__ h0b, ushort* __restrict__ h1b,
    ushort* __restrict__ h1hist, unsigned* __restrict__ flags){
  __shared__ ushort Wlds0[32*808];   // rows padded 800->808
  __shared__ ushort Wlds1[32*1032];  // 1024->1032
  __shared__ float pc0[32][33];
  __shared__ float pc1[32][33];

  const int tid  = threadIdx.x;
  const int bid  = blockIdx.x;
  const int u0   = bid << 3;
  const int wave = tid >> 6;
  const int lane = tid & 63;
  const int col  = lane & 15;
  const int kg   = lane >> 4;
  const int mh   = wave & 1;
  const int nh   = wave >> 1;
  const int arow = (mh<<4) + col;          // batch row for A-frag
  const int nlo  = (nh<<4) + col;          // local gate-row for B-frag

  for (int v = tid; v < 3200; v += 256){
    int r = v/100, c8 = v - r*100;
    int grow = ((r>>3)<<9) + u0 + (r&7);
    *(short8*)&Wlds0[r*808 + c8*8] = *(const short8*)(W0g + (size_t)grow*K0 + c8*8);
  }
  for (int v = tid; v < 4096; v += 256){
    int r = v>>7, c8 = v&127;
    int grow = ((r>>3)<<9) + u0 + (r&7);
    *(short8*)&Wlds1[r*1032 + c8*8] = *(const short8*)(W1g + (size_t)grow*K1 + c8*8);
  }
  const int bb = tid & 31;
  const int ul = tid >> 5;
  const int u  = u0 + ul;
  float bc0r[4], bc1r[4];
  #pragma unroll
  for (int g=0; g<4; g++){ bc0r[g] = b0c[(g<<9)+u]; bc1r[g] = b1c[(g<<9)+u]; }
  float c0r = 0.f, c1r = 0.f;
  const ushort* wb0 = &Wlds0[nlo*808];
  const ushort* wb1 = &Wlds1[nlo*1032];
  __syncthreads();

  // prefetch x-part of layer0 for t=0
  f32x4 acc0x = {0.f,0.f,0.f,0.f};
  {
    const ushort* xt = hlnb;
    #pragma unroll
    for (int kt=0; kt<9; kt++){
      short8 a = *(const short8*)(xt + arow*NFP + kt*32 + kg*8);
      short8 b = *(const short8*)(wb0 + kt*32 + kg*8);
      acc0x = __builtin_amdgcn_mfma_f32_16x16x32_bf16(a, b, acc0x, 0, 0, 0);
    }
  }

  for (int t = 0; t <= NT; ++t){
    const ushort* h0p = h0b + (size_t)((t-1)&1)*(BATCH*HID);
    f32x4 acc0 = acc0x;
    f32x4 acc1 = {0.f,0.f,0.f,0.f};
    if (t >= 1){                           // layer1, tau = t-1
      const ushort* h1p = h1b + (size_t)((t-2)&1)*(BATCH*HID);
      #pragma unroll
      for (int kt=0; kt<16; kt++){
        short8 a = *(const short8*)(h0p + arow*HID + kt*32 + kg*8);
        short8 b = *(const short8*)(wb1 + kt*32 + kg*8);
        acc1 = __builtin_amdgcn_mfma_f32_16x16x32_bf16(a, b, acc1, 0, 0, 0);
      }
      #pragma unroll
      for (int kt=0; kt<16; kt++){
        short8 a = *(const short8*)(h1p + arow*HID + kt*32 + kg*8);
        short8 b = *(const short8*)(wb1 + 512 + kt*32 + kg*8);
        acc1 = __builtin_amdgcn_mfma_f32_16x16x32_bf16(a, b, acc1, 0, 0, 0);
      }
    }
    if (t < NT){                           // layer0 h-part, step t
      #pragma unroll
      for (int kt=0; kt<16; kt++){
        short8 a = *(const short8*)(h0p + arow*HID + kt*32 + kg*8);
        short8 b = *(const short8*)(wb0 + 288 + kt*32 + kg*8);
        acc0 = __builtin_amdgcn_mfma_f32_16x16x32_bf16(a, b, acc0, 0, 0, 0);
      }
    }
    if (t < NT){
      #pragma unroll
      for (int j=0;j<4;j++) pc0[(mh<<4)+(kg<<2)+j][nlo] = acc0[j];
    }
    if (t >= 1){
      #pragma unroll
      for (int j=0;j<4;j++) pc1[(mh<<4)+(kg<<2)+j][nlo] = acc1[j];
    }
    __syncthreads();
    // ---- gate phase ----
    if (t < NT){
      float p0 = pc0[bb][0*8+ul] + bc0r[0];
      float p1 = pc0[bb][1*8+ul] + bc0r[1];
      float p2 = pc0[bb][2*8+ul] + bc0r[2];
      float p3 = pc0[bb][3*8+ul] + bc0r[3];
      float cn = sigm(p1)*c0r + sigm(p0)*tanhf(p2);
      float hn = sigm(p3)*tanhf(cn);
      c0r = cn;
      h0b[(size_t)(t&1)*(BATCH*HID) + bb*HID + u] = f2bf(hn);
    }
    if (t >= 1){
      float p0 = pc1[bb][0*8+ul] + bc1r[0];
      float p1 = pc1[bb][1*8+ul] + bc1r[1];
      float p2 = pc1[bb][2*8+ul] + bc1r[2];
      float p3 = pc1[bb][3*8+ul] + bc1r[3];
      float cn = sigm(p1)*c1r + sigm(p0)*tanhf(p2);
      float hn = sigm(p3)*tanhf(cn);
      c1r = cn;
      ushort hb = f2bf(hn);
      h1b[(size_t)((t-1)&1)*(BATCH*HID) + bb*HID + u] = hb;
      __builtin_nontemporal_store(hb, h1hist + (size_t)t*(BATCH*HID) + bb*HID + u);
    }
    __syncthreads();                       // all h writes issued & ordered within block
    if (tid == 0)                          // arrive: RELEASE store to OWN line (no RMW)
      __hip_atomic_store(&flags[bid*32], (unsigned)(t+1), __ATOMIC_RELEASE, __HIP_MEMORY_SCOPE_AGENT);
    // overlap: h-independent x-part of layer0 for step t+1
    acc0x = f32x4{0.f,0.f,0.f,0.f};
    if (t+1 < NT){
      const ushort* xt = hlnb + (size_t)(t+1)*BATCH*NFP;
      #pragma unroll
      for (int kt=0; kt<9; kt++){
        short8 a = *(const short8*)(xt + arow*NFP + kt*32 + kg*8);
        short8 b = *(const short8*)(wb0 + kt*32 + kg*8);
        acc0x = __builtin_amdgcn_mfma_f32_16x16x32_bf16(a, b, acc0x, 0, 0, 0);
      }
    }
    if (wave == 0){                        // wait: 64-lane gather poll, no RMW, no hot line
      unsigned tgt = (unsigned)(t+1);
      while (true){
        unsigned v = __hip_atomic_load(&flags[lane*32], __ATOMIC_RELAXED, __HIP_MEMORY_SCOPE_AGENT);
        if (__all(v >= tgt)) break;
        __builtin_amdgcn_s_sleep(1);
      }
      (void)__hip_atomic_load(&flags[lane*32], __ATOMIC_ACQUIRE, __HIP_MEMORY_SCOPE_AGENT);
    }
    __syncthreads();
  }
}

// ---------------- STFT for a tail chunk (rotation DFT) ----------------
__global__ __launch_bounds__(256) void k_stft_chunk(const float* __restrict__ x, const float* __restrict__ tw,
                                                    float* __restrict__ spR, float* __restrict__ spI, int tb0){
  int tt = blockIdx.x;
  int b  = blockIdx.y;
  int t  = tb0 + tt;
  if (t < 0 || t >= NT){
    for (int f = threadIdx.x; f < NF; f += 256){
      size_t o = ((size_t)b*NF + f)*36 + tt;
      spR[o]=0.f; spI[o]=0.f;
    }
    return;
  }
  __shared__ float fr[NFFT];
  const float* xb = x + (size_t)b*LEN;
  for (int n = threadIdx.x; n < NFFT; n += 256){
    int j = t*256 + n - 256;
    if (j < 0) j = -j;
    else if (j >= LEN) j = 2*LEN - 2 - j;
    fr[n] = xb[j] * (0.5f - 0.5f*tw[n]);
  }
  __syncthreads();
  for (int f = threadIdx.x; f < NF; f += 256){
    float c1 = tw[f], s1 = tw[512+f];
    float cr = 1.f, si = 0.f;
    float ar = 0.f, ai = 0.f;
    #pragma unroll 8
    for (int n = 0; n < NFFT; n++){
      float vv = fr[n];
      ar += vv*cr;
      ai -= vv*si;
      float cn = cr*c1 - si*s1;
      si = cr*s1 + si*c1;
      cr = cn;
    }
    size_t o = ((size_t)b*NF + f)*36 + tt;
    spR[o] = ar; spI[o] = ai;
  }
}

// ---------------- MFMA GEMM: C[M,N] = A_bf16[M,512] * Bb_bf16[N,512]^T + bias, tanh ----------------
__global__ __launch_bounds__(256) void k_gemm_mfma(const ushort* __restrict__ A, const ushort* __restrict__ Bb,
                                                   const float* __restrict__ bias,
                                                   float* __restrict__ C, int M, int N){
  int bm = blockIdx.y*64, bn = blockIdx.x*64;
  int wave = threadIdx.x >> 6, lane = threadIdx.x & 63;
  int wm = wave >> 1, wn = wave & 1;
  int col = lane & 15, kg = lane >> 4;
  f32x4 acc00={0.f,0.f,0.f,0.f}, acc01=acc00, acc10=acc00, acc11=acc00;
  const ushort* Ap = A + (size_t)(bm + wm*32)*512;
  int nr0 = bn + wn*32 + col;
  int nr1 = nr0 + 16;
  const ushort* Bp0 = Bb + (size_t)((nr0<N)?nr0:0)*512;
  const ushort* Bp1 = Bb + (size_t)((nr1<N)?nr1:0)*512;
  #pragma unroll 4
  for (int k0=0; k0<512; k0+=32){
    short8 a0 = *(const short8*)(Ap + (size_t)col*512 + k0 + kg*8);
    short8 a1 = *(const short8*)(Ap + (size_t)(16+col)*512 + k0 + kg*8);
    short8 b0 = *(const short8*)(Bp0 + k0 + kg*8);
    short8 b1 = *(const short8*)(Bp1 + k0 + kg*8);
    acc00 = __builtin_amdgcn_mfma_f32_16x16x32_bf16(a0, b0, acc00, 0, 0, 0);
    acc01 = __builtin_amdgcn_mfma_f32_16x16x32_bf16(a0, b1, acc01, 0, 0, 0);
    acc10 = __builtin_amdgcn_mfma_f32_16x16x32_bf16(a1, b0, acc10, 0, 0, 0);
    acc11 = __builtin_amdgcn_mfma_f32_16x16x32_bf16(a1, b1, acc11, 0, 0, 0);
  }
  #define STORE_ACC(ACC, MI, NI) { \
    int n = bn + wn*32 + (NI)*16 + col; \
    if (n < N){ \
      float bv = bias[n]; \
      _Pragma("unroll") \
      for (int j=0;j<4;j++){ \
        int m = bm + wm*32 + (MI)*16 + kg*4 + j; \
        C[(size_t)m*N + n] = tanhf(ACC[j] + bv); \
      } \
    } }
  STORE_ACC(acc00, 0, 0)
  STORE_ACC(acc01, 0, 1)
  STORE_ACC(acc10, 1, 0)
  STORE_ACC(acc11, 1, 1)
  #undef STORE_ACC
}

// ---------------- fused deep-filter + irfft(rotation) + window + OLA(atomic) ----------------
__global__ __launch_bounds__(256) void k_ifused(const float* __restrict__ prch,
    const float* __restrict__ spR, const float* __restrict__ spI,
    const float* __restrict__ tw, float* __restrict__ out, int tb0){
  int tl = blockIdx.x >> 6;
  int b  = (blockIdx.x >> 1) & 31;
  int s  = blockIdx.x & 1;
  int tau = tb0 + 4 + tl;
  __shared__ float re[NF], im[NF];
  const float* p = prch + ((size_t)tl*BATCH + b)*PROJN;
  for (int f=threadIdx.x; f<NF; f+=256){
    float ar=0.f, ai=0.f;
    size_t so = ((size_t)b*NF + f)*36;
    #pragma unroll
    for (int d=0; d<5; d++){
      int ts = tb0 + tl + d;
      if (ts >= 0){
        float sr=spR[so + tl + d], si=spI[so + tl + d];
        float cr=p[d*514 + s*257 + f];
        float ci=p[2570 + d*514 + s*257 + f];
        ar += sr*cr - si*ci;
        ai += sr*ci + si*cr;
      }
    }
    re[f]=ar; im[f]=ai;
  }
  __syncthreads();
  float* ob = out + (size_t)(b*2+s)*LEN;
  for (int n=threadIdx.x; n<NFFT; n+=256){
    float c1 = tw[n], s1 = tw[512+n];
    float acc = re[0] + ((n&1) ? -re[256] : re[256]);
    float cr = c1, si = s1;
    #pragma unroll 8
    for (int k=1; k<256; k++){
      acc += 2.f*(re[k]*cr - im[k]*si);
      float cn = cr*c1 - si*s1;
      si = cr*s1 + si*c1;
      cr = cn;
    }
    int pos = tau*256 - 256 + n;
    if (pos >= 0 && pos < LEN)
      atomicAdd(ob + pos, acc * (1.0f/512.0f) * (0.5f - 0.5f*c1));
  }
}

// ---------------- normalize by wsq ----------------
__global__ __launch_bounds__(256) void k_norm(float* __restrict__ out, const float* __restrict__ tw, int n){
  for (int i = blockIdx.x*256 + threadIdx.x; i < n; i += gridDim.x*256){
    int m = (i % LEN) & 255;
    float cm = tw[m];
    float w1 = 0.5f - 0.5f*cm;
    float w2 = 0.5f + 0.5f*cm;
    out[i] = out[i] / (w1*w1 + w2*w2);
  }
}

extern "C" void kernel_launch(void* const* d_in, const int* in_sizes, int n_in,
                              void* d_out, int out_size, void* d_ws, size_t ws_size,
                              hipStream_t stream){
  const float* x     = (const float*)d_in[0];
  const float* ln_g  = (const float*)d_in[1];
  const float* ln_b  = (const float*)d_in[2];
  const float* Wih0  = (const float*)d_in[3];
  const float* Whh0  = (const float*)d_in[4];
  const float* bih0  = (const float*)d_in[5];
  const float* bhh0  = (const float*)d_in[6];
  const float* Wih1  = (const float*)d_in[7];
  const float* Whh1  = (const float*)d_in[8];
  const float* bih1  = (const float*)d_in[9];
  const float* bhh1  = (const float*)d_in[10];
  const float* projW = (const float*)d_in[11];
  const float* projb = (const float*)d_in[12];

  char* base = (char*)d_ws;
  size_t off = 0;
  auto carve = [&](size_t bytes)->char*{
    char* p = base + off;
    off += (bytes + 255) & ~(size_t)255;
    return p;
  };
  float*  tw     = (float*) carve(1024*4);
  ushort* hlnb   = (ushort*)carve((size_t)NT*BATCH*NFP*2);
  ushort* W0     = (ushort*)carve((size_t)2048*K0*2);
  ushort* W1     = (ushort*)carve((size_t)2048*K1*2);
  float*  b0c    = (float*) carve(2048*4);
  float*  b1c    = (float*) carve(2048*4);
  ushort* projWb = (ushort*)carve((size_t)PROJN*HID*2);
  ushort* h0b    = (ushort*)carve((size_t)2*BATCH*HID*2);   // 65536B
  ushort* h1b    = (ushort*)carve((size_t)2*BATCH*HID*2);   // 65536B
  unsigned* flags= (unsigned*)carve(NBLK*32*4);             // 8192B, 128B-spaced slots
  ushort* h1hist = (ushort*)carve((size_t)(NT+1)*BATCH*HID*2);
  float*  spR    = (float*) carve((size_t)BATCH*NF*36*4);
  float*  spI    = (float*) carve((size_t)BATCH*NF*36*4);
  float*  prch   = (float*) carve((size_t)TC*BATCH*PROJN*4);

  int nzInts = (int)((65536 + 65536 + NBLK*32*4) / 4);   // h0b, h1b, flags contiguous

  k_init<<<512, 256, 0, stream>>>(tw, (int*)h0b, nzInts);
  k_zero<<<2048, 256, 0, stream>>>((float*)d_out, out_size);
  k_prep<<<4096, 256, 0, stream>>>(Wih0, Whh0, bih0, bhh0, Wih1, Whh1, bih1, bhh1,
                                   projW, W0, W1, b0c, b1c, projWb);
  k_stftln<<<BATCH*NT, 256, 0, stream>>>(x, tw, ln_g, ln_b, hlnb);

  {
    void* args[] = { (void*)&hlnb, (void*)&W0, (void*)&W1, (void*)&b0c, (void*)&b1c,
                     (void*)&h0b, (void*)&h1b, (void*)&h1hist, (void*)&flags };
    hipLaunchCooperativeKernel(reinterpret_cast<void*>(k_lstm), dim3(NBLK), dim3(256),
                               args, 0, stream);
  }

  for (int c = 0; c < NCHUNK; ++c){
    int tb0 = c*TC - 4;
    int tcc = (c == NCHUNK-1) ? (NT - c*TC) : TC;
    k_stft_chunk<<<dim3(36, BATCH), 256, 0, stream>>>(x, tw, spR, spI, tb0);
    dim3 gp((PROJN+63)/64, (tcc*BATCH)/64);
    k_gemm_mfma<<<gp, 256, 0, stream>>>(h1hist + ((size_t)(c*TC)+1)*BATCH*HID, projWb, projb,
                                        prch, tcc*BATCH, PROJN);
    k_ifused<<<tcc*64, 256, 0, stream>>>(prch, spR, spI, tw, (float*)d_out, tb0);
  }

  k_norm<<<2048, 256, 0, stream>>>((float*)d_out, tw, out_size);
}